// Round 1
// baseline (1505.767 us; speedup 1.0000x reference)
//
#include <hip/hip_runtime.h>
#include <hip/hip_bf16.h>

// ---------------- problem dims ----------------
#define D_MODEL 1024
#define D_INNER 2048
#define D_STATE 16
#define D_CONVK 4
#define DT_RANK 64
#define BATCH   2
#define SEQ     1024
#define NROWS   (BATCH*SEQ)          // 2048 rows (b*s flattened)

// ---------------- ws layout (float elements) ----------------
// xz  [2048][4096]  (x_in cols 0..2047, z cols 2048..4095)
// xc  [2048][2048]
// dbl [2048][96]    (dt_low 0..63 | B 64..79 | C 80..95)
// dt  [2048][2048]
// yg  [2048][2048]
#define XZ_OFF  0
#define XZ_SZ   (NROWS*2*D_INNER)
#define XC_OFF  (XZ_OFF + XZ_SZ)
#define XC_SZ   (NROWS*D_INNER)
#define DBL_OFF (XC_OFF + XC_SZ)
#define DBL_SZ  (NROWS*96)
#define DT_OFF  (DBL_OFF + DBL_SZ)
#define DT_SZ   (NROWS*D_INNER)
#define YG_OFF  (DT_OFF + DT_SZ)
#define YG_SZ   (NROWS*D_INNER)
// total = 21,168,128 floats = 84.7 MB

// ======================================================================
// f32 SIMT GEMM:  C[M][N] = A[M][lda(K used)] * B[N][ldb]^T
// 128x128 tile, BK=16, 256 threads, 8x8 per-thread microtile.
// ======================================================================
#define BM 128
#define BN 128
#define BKG 16

__global__ __launch_bounds__(256) void gemm_f32_nt(
    const float* __restrict__ A, int lda,
    const float* __restrict__ B, int ldb,
    float* __restrict__ C, int ldc,
    int M, int N, int K)
{
  __shared__ float As[BKG][BM + 4];   // +4 pad: keeps 16B alignment, breaks bank stride
  __shared__ float Bs[BKG][BN + 4];

  const int tid = threadIdx.x;
  const int bm = blockIdx.y * BM;
  const int bn = blockIdx.x * BN;
  const int tm = tid >> 4;          // 0..15
  const int tn = tid & 15;          // 0..15
  const int ar = tid >> 2;          // staging row 0..63
  const int ac = (tid & 3) * 4;     // staging col {0,4,8,12}

  float acc[8][8];
#pragma unroll
  for (int i = 0; i < 8; ++i)
#pragma unroll
    for (int j = 0; j < 8; ++j) acc[i][j] = 0.f;

  for (int k0 = 0; k0 < K; k0 += BKG) {
#pragma unroll
    for (int half = 0; half < 2; ++half) {
      const int row = ar + half * 64;
      // A tile
      {
        const int gm = bm + row;
        float4 v = make_float4(0.f, 0.f, 0.f, 0.f);
        if (gm < M) v = *(const float4*)(A + (size_t)gm * lda + k0 + ac);
        As[ac + 0][row] = v.x; As[ac + 1][row] = v.y;
        As[ac + 2][row] = v.z; As[ac + 3][row] = v.w;
      }
      // B tile
      {
        const int gn = bn + row;
        float4 v = make_float4(0.f, 0.f, 0.f, 0.f);
        if (gn < N) v = *(const float4*)(B + (size_t)gn * ldb + k0 + ac);
        Bs[ac + 0][row] = v.x; Bs[ac + 1][row] = v.y;
        Bs[ac + 2][row] = v.z; Bs[ac + 3][row] = v.w;
      }
    }
    __syncthreads();

#pragma unroll
    for (int kk = 0; kk < BKG; ++kk) {
      const float4 a0 = *(const float4*)&As[kk][tm * 8];
      const float4 a1 = *(const float4*)&As[kk][tm * 8 + 4];
      const float4 b0 = *(const float4*)&Bs[kk][tn * 8];
      const float4 b1 = *(const float4*)&Bs[kk][tn * 8 + 4];
      const float a[8] = {a0.x,a0.y,a0.z,a0.w,a1.x,a1.y,a1.z,a1.w};
      const float b[8] = {b0.x,b0.y,b0.z,b0.w,b1.x,b1.y,b1.z,b1.w};
#pragma unroll
      for (int i = 0; i < 8; ++i)
#pragma unroll
        for (int j = 0; j < 8; ++j)
          acc[i][j] = fmaf(a[i], b[j], acc[i][j]);
    }
    __syncthreads();
  }

#pragma unroll
  for (int i = 0; i < 8; ++i) {
    const int gm = bm + tm * 8 + i;
    if (gm >= M) continue;
    const int gn0 = bn + tn * 8;
    if (gn0 + 7 < N) {
      *(float4*)(C + (size_t)gm * ldc + gn0)     = make_float4(acc[i][0], acc[i][1], acc[i][2], acc[i][3]);
      *(float4*)(C + (size_t)gm * ldc + gn0 + 4) = make_float4(acc[i][4], acc[i][5], acc[i][6], acc[i][7]);
    } else {
#pragma unroll
      for (int j = 0; j < 8; ++j)
        if (gn0 + j < N) C[(size_t)gm * ldc + gn0 + j] = acc[i][j];
    }
  }
}

// ======================================================================
// depthwise causal conv1d + SiLU:  xc[m][d] = silu(b_conv[d] + sum_k W[d][k]*x_in[b, s+k-3, d])
// ======================================================================
__global__ __launch_bounds__(256) void conv_silu_kernel(
    const float* __restrict__ xz, const float* __restrict__ Wc,
    const float* __restrict__ bc, float* __restrict__ xc)
{
  const int idx = blockIdx.x * 256 + threadIdx.x;   // over 2048*2048
  const int d = idx & (D_INNER - 1);
  const int m = idx >> 11;
  const int s = m & (SEQ - 1);
  const int mb = m - s;                              // b*SEQ
  float acc = bc[d];
#pragma unroll
  for (int k = 0; k < D_CONVK; ++k) {
    const int t = s + k - (D_CONVK - 1);
    if (t >= 0)
      acc = fmaf(Wc[d * D_CONVK + k], xz[(size_t)(mb + t) * (2 * D_INNER) + d], acc);
  }
  xc[idx] = acc / (1.f + __expf(-acc));              // SiLU
}

// ======================================================================
// dt activation: dt = softplus(raw + b_dt) + 1e-4   (in place)
// ======================================================================
__global__ __launch_bounds__(256) void dt_act_kernel(
    float* __restrict__ dt, const float* __restrict__ b_dt)
{
  const int idx = blockIdx.x * 256 + threadIdx.x;    // over 2048*2048
  const int d = idx & (D_INNER - 1);
  const float v = dt[idx] + b_dt[d];
  const float sp = (v > 20.f) ? v : log1pf(__expf(v));
  dt[idx] = sp + 1e-4f;
}

// ======================================================================
// selective scan, n-in-lane: 16 lanes per (b,d) chain.
// Fuses dA=exp(clip(dt*A)), dBu, y=<h,C>, D-skip, SiLU(z) gate.
// ======================================================================
#define SCH 128
__global__ __launch_bounds__(256) void scan_kernel(
    const float* __restrict__ dtv, const float* __restrict__ xc,
    const float* __restrict__ dbl, const float* __restrict__ A_log,
    const float* __restrict__ Dp,  const float* __restrict__ xz,
    float* __restrict__ yg)
{
  __shared__ float sBC[SCH][32];
  __shared__ float sDT[SCH][16];
  __shared__ float sXC[SCH][16];

  const int tid = threadIdx.x;
  const int cl = tid >> 4;                     // chain-local 0..15
  const int n  = tid & 15;                     // state index
  const int c  = blockIdx.x * 16 + cl;         // global chain
  const int b  = c >> 11;
  const int d  = c & (D_INNER - 1);
  const int d_base = (blockIdx.x * 16) & (D_INNER - 1);
  const int rowbase = b * SEQ;

  const float A_dn = -__expf(A_log[d * D_STATE + n]);
  const float Dd = Dp[d];
  float h = 0.f;

  for (int s0 = 0; s0 < SEQ; s0 += SCH) {
    __syncthreads();
    for (int idx = tid; idx < SCH * 32; idx += 256) {
      const int i = idx >> 5, j = idx & 31;
      sBC[i][j] = dbl[(size_t)(rowbase + s0 + i) * 96 + 64 + j];
    }
    for (int idx = tid; idx < SCH * 16; idx += 256) {
      const int i = idx >> 4, j = idx & 15;
      const size_t off = (size_t)(rowbase + s0 + i) * D_INNER + d_base + j;
      sDT[i][j] = dtv[off];
      sXC[i][j] = xc[off];
    }
    __syncthreads();

    for (int i = 0; i < SCH; ++i) {
      const float dt_v = sDT[i][cl];
      const float xc_v = sXC[i][cl];
      const float Bn = sBC[i][n];
      const float Cn = sBC[i][16 + n];
      float t1 = dt_v * A_dn;
      t1 = fminf(fmaxf(t1, -10.f), 10.f);
      const float dA = __expf(t1);
      h = fmaf(dA, h, dt_v * Bn * xc_v);
      float yp = h * Cn;
      yp += __shfl_xor(yp, 1, 16);
      yp += __shfl_xor(yp, 2, 16);
      yp += __shfl_xor(yp, 4, 16);
      yp += __shfl_xor(yp, 8, 16);
      if (n == 0) {
        const int m = rowbase + s0 + i;
        const float zv = xz[(size_t)m * (2 * D_INNER) + D_INNER + d];
        const float sil = zv / (1.f + __expf(-zv));
        yg[(size_t)m * D_INNER + d] = (yp + xc_v * Dd) * sil;
      }
    }
  }
}

// ======================================================================
// RMSNorm over d_inner per row, in place on yg.
// ======================================================================
__global__ __launch_bounds__(256) void rms_kernel(
    float* __restrict__ yg, const float* __restrict__ rms_w)
{
  const int m = blockIdx.x;
  float* row = yg + (size_t)m * D_INNER;
  const int e0 = threadIdx.x * 8;
  float4 v0 = *(float4*)&row[e0];
  float4 v1 = *(float4*)&row[e0 + 4];
  float ss = v0.x*v0.x + v0.y*v0.y + v0.z*v0.z + v0.w*v0.w
           + v1.x*v1.x + v1.y*v1.y + v1.z*v1.z + v1.w*v1.w;
#pragma unroll
  for (int off = 32; off > 0; off >>= 1) ss += __shfl_down(ss, off);
  __shared__ float wsum[4];
  const int lane = threadIdx.x & 63, wid = threadIdx.x >> 6;
  if (lane == 0) wsum[wid] = ss;
  __syncthreads();
  const float total = wsum[0] + wsum[1] + wsum[2] + wsum[3];
  const float scale = rsqrtf(total / (float)D_INNER + 1e-6f);
  const float4 w0 = *(const float4*)&rms_w[e0];
  const float4 w1 = *(const float4*)&rms_w[e0 + 4];
  v0.x *= scale * w0.x; v0.y *= scale * w0.y; v0.z *= scale * w0.z; v0.w *= scale * w0.w;
  v1.x *= scale * w1.x; v1.y *= scale * w1.y; v1.z *= scale * w1.z; v1.w *= scale * w1.w;
  *(float4*)&row[e0] = v0;
  *(float4*)&row[e0 + 4] = v1;
}

// ======================================================================
extern "C" void kernel_launch(void* const* d_in, const int* in_sizes, int n_in,
                              void* d_out, int out_size, void* d_ws, size_t ws_size,
                              hipStream_t stream) {
  const float* x      = (const float*)d_in[0];
  const float* W_in   = (const float*)d_in[1];
  const float* W_conv = (const float*)d_in[2];
  const float* b_conv = (const float*)d_in[3];
  const float* W_x    = (const float*)d_in[4];
  const float* W_dt   = (const float*)d_in[5];
  const float* b_dt   = (const float*)d_in[6];
  const float* A_log  = (const float*)d_in[7];
  const float* Dp     = (const float*)d_in[8];
  const float* rms_w  = (const float*)d_in[9];
  const float* W_out  = (const float*)d_in[10];
  float* out = (float*)d_out;
  float* ws  = (float*)d_ws;

  float* xz  = ws + XZ_OFF;
  float* xc  = ws + XC_OFF;
  float* dbl = ws + DBL_OFF;
  float* dt  = ws + DT_OFF;
  float* yg  = ws + YG_OFF;

  // 1. in_proj: xz = x @ W_in^T   [2048,1024]x[4096,1024]^T
  {
    dim3 g((2 * D_INNER) / BN, NROWS / BM);
    gemm_f32_nt<<<g, 256, 0, stream>>>(x, D_MODEL, W_in, D_MODEL, xz, 2 * D_INNER,
                                       NROWS, 2 * D_INNER, D_MODEL);
  }
  // 2. conv + silu -> xc
  conv_silu_kernel<<<(NROWS * D_INNER) / 256, 256, 0, stream>>>(xz, W_conv, b_conv, xc);
  // 3. x_proj: dbl = xc @ W_x^T   [2048,2048]x[96,2048]^T
  {
    dim3 g(1, NROWS / BM);
    gemm_f32_nt<<<g, 256, 0, stream>>>(xc, D_INNER, W_x, D_INNER, dbl, 96,
                                       NROWS, 96, D_INNER);
  }
  // 4. dt_proj: dt_raw = dbl[:, :64] @ W_dt^T  [2048,64(stride96)]x[2048,64]^T
  {
    dim3 g(D_INNER / BN, NROWS / BM);
    gemm_f32_nt<<<g, 256, 0, stream>>>(dbl, 96, W_dt, DT_RANK, dt, D_INNER,
                                       NROWS, D_INNER, DT_RANK);
  }
  // 5. dt = softplus(dt_raw + b_dt) + 1e-4
  dt_act_kernel<<<(NROWS * D_INNER) / 256, 256, 0, stream>>>(dt, b_dt);
  // 6. fused selective scan + D-skip + SiLU(z) gate -> yg
  scan_kernel<<<(BATCH * D_INNER) / 16, 256, 0, stream>>>(dt, xc, dbl, A_log, Dp, xz, yg);
  // 7. RMSNorm (in place)
  rms_kernel<<<NROWS, 256, 0, stream>>>(yg, rms_w);
  // 8. out_proj: out = yg @ W_out^T  [2048,2048]x[1024,2048]^T
  {
    dim3 g(D_MODEL / BN, NROWS / BM);
    gemm_f32_nt<<<g, 256, 0, stream>>>(yg, D_INNER, W_out, D_INNER, out, D_MODEL,
                                       NROWS, D_MODEL, D_INNER);
  }
}

// Round 2
// 1084.628 us; speedup vs baseline: 1.3883x; 1.3883x over previous
//
#include <hip/hip_runtime.h>
#include <hip/hip_bf16.h>

// ---------------- problem dims ----------------
#define D_MODEL 1024
#define D_INNER 2048
#define D_STATE 16
#define D_CONVK 4
#define DT_RANK 64
#define BATCH   2
#define SEQ     1024
#define NROWS   (BATCH*SEQ)          // 2048 rows (b*s flattened)

// scan chunking
#define NCHUNK  16
#define CHUNK   (SEQ/NCHUNK)         // 64

// ---------------- ws layout (float elements) ----------------
// xz  [2048][4096]  (x_in cols 0..2047 — dead after conv, reused for P/L/HST; z cols 2048..4095)
// xc  [2048][2048]
// dbl [2048][96]    (dt_low 0..63 | B 64..79 | C 80..95)
// dt  [2048][2048]
// yg  [2048][2048]
#define XZ_OFF  0
#define XZ_SZ   (NROWS*2*D_INNER)
#define XC_OFF  (XZ_OFF + XZ_SZ)
#define XC_SZ   (NROWS*D_INNER)
#define DBL_OFF (XC_OFF + XC_SZ)
#define DBL_SZ  (NROWS*96)
#define DT_OFF  (DBL_OFF + DBL_SZ)
#define DT_SZ   (NROWS*D_INNER)
#define YG_OFF  (DT_OFF + DT_SZ)
#define YG_SZ   (NROWS*D_INNER)
// total = 21,168,128 floats = 84.7 MB (unchanged)

// P/L/HST packed into the x_in half of xz (2048 rows x 2048 usable cols, row stride 4096).
// flat idx i -> xz[(i>>11)*4096 + (i&2047)]. Each slice = NCHUNK*BATCH*D_INNER*16 = 1M floats.
#define PLH_SLICE (1<<20)
__device__ __forceinline__ float& plh_at(float* xz, int i) {
  return xz[((size_t)(i >> 11)) * (2 * D_INNER) + (i & (D_INNER - 1))];
}

// ======================================================================
// f32 SIMT GEMM:  C[M][N] = A[M][lda(K used)] * B[N][ldb]^T
// 128x128 tile, BK=16, 256 threads, 8x8 per-thread microtile.
// ======================================================================
#define BM 128
#define BN 128
#define BKG 16

__global__ __launch_bounds__(256) void gemm_f32_nt(
    const float* __restrict__ A, int lda,
    const float* __restrict__ B, int ldb,
    float* __restrict__ C, int ldc,
    int M, int N, int K)
{
  __shared__ float As[BKG][BM + 4];
  __shared__ float Bs[BKG][BN + 4];

  const int tid = threadIdx.x;
  const int bm = blockIdx.y * BM;
  const int bn = blockIdx.x * BN;
  const int tm = tid >> 4;          // 0..15
  const int tn = tid & 15;          // 0..15
  const int ar = tid >> 2;          // staging row 0..63
  const int ac = (tid & 3) * 4;     // staging col {0,4,8,12}

  float acc[8][8];
#pragma unroll
  for (int i = 0; i < 8; ++i)
#pragma unroll
    for (int j = 0; j < 8; ++j) acc[i][j] = 0.f;

  for (int k0 = 0; k0 < K; k0 += BKG) {
#pragma unroll
    for (int half = 0; half < 2; ++half) {
      const int row = ar + half * 64;
      {
        const int gm = bm + row;
        float4 v = make_float4(0.f, 0.f, 0.f, 0.f);
        if (gm < M) v = *(const float4*)(A + (size_t)gm * lda + k0 + ac);
        As[ac + 0][row] = v.x; As[ac + 1][row] = v.y;
        As[ac + 2][row] = v.z; As[ac + 3][row] = v.w;
      }
      {
        const int gn = bn + row;
        float4 v = make_float4(0.f, 0.f, 0.f, 0.f);
        if (gn < N) v = *(const float4*)(B + (size_t)gn * ldb + k0 + ac);
        Bs[ac + 0][row] = v.x; Bs[ac + 1][row] = v.y;
        Bs[ac + 2][row] = v.z; Bs[ac + 3][row] = v.w;
      }
    }
    __syncthreads();

#pragma unroll
    for (int kk = 0; kk < BKG; ++kk) {
      const float4 a0 = *(const float4*)&As[kk][tm * 8];
      const float4 a1 = *(const float4*)&As[kk][tm * 8 + 4];
      const float4 b0 = *(const float4*)&Bs[kk][tn * 8];
      const float4 b1 = *(const float4*)&Bs[kk][tn * 8 + 4];
      const float a[8] = {a0.x,a0.y,a0.z,a0.w,a1.x,a1.y,a1.z,a1.w};
      const float b[8] = {b0.x,b0.y,b0.z,b0.w,b1.x,b1.y,b1.z,b1.w};
#pragma unroll
      for (int i = 0; i < 8; ++i)
#pragma unroll
        for (int j = 0; j < 8; ++j)
          acc[i][j] = fmaf(a[i], b[j], acc[i][j]);
    }
    __syncthreads();
  }

#pragma unroll
  for (int i = 0; i < 8; ++i) {
    const int gm = bm + tm * 8 + i;
    if (gm >= M) continue;
    const int gn0 = bn + tn * 8;
    if (gn0 + 7 < N) {
      *(float4*)(C + (size_t)gm * ldc + gn0)     = make_float4(acc[i][0], acc[i][1], acc[i][2], acc[i][3]);
      *(float4*)(C + (size_t)gm * ldc + gn0 + 4) = make_float4(acc[i][4], acc[i][5], acc[i][6], acc[i][7]);
    } else {
#pragma unroll
      for (int j = 0; j < 8; ++j)
        if (gn0 + j < N) C[(size_t)gm * ldc + gn0 + j] = acc[i][j];
    }
  }
}

// ======================================================================
// depthwise causal conv1d + SiLU
// ======================================================================
__global__ __launch_bounds__(256) void conv_silu_kernel(
    const float* __restrict__ xz, const float* __restrict__ Wc,
    const float* __restrict__ bc, float* __restrict__ xc)
{
  const int idx = blockIdx.x * 256 + threadIdx.x;   // over 2048*2048
  const int d = idx & (D_INNER - 1);
  const int m = idx >> 11;
  const int s = m & (SEQ - 1);
  const int mb = m - s;                              // b*SEQ
  float acc = bc[d];
#pragma unroll
  for (int k = 0; k < D_CONVK; ++k) {
    const int t = s + k - (D_CONVK - 1);
    if (t >= 0)
      acc = fmaf(Wc[d * D_CONVK + k], xz[(size_t)(mb + t) * (2 * D_INNER) + d], acc);
  }
  xc[idx] = acc / (1.f + __expf(-acc));              // SiLU
}

// ======================================================================
// dt activation: dt = softplus(raw + b_dt) + 1e-4   (in place)
// ======================================================================
__global__ __launch_bounds__(256) void dt_act_kernel(
    float* __restrict__ dt, const float* __restrict__ b_dt)
{
  const int idx = blockIdx.x * 256 + threadIdx.x;    // over 2048*2048
  const int d = idx & (D_INNER - 1);
  const float v = dt[idx] + b_dt[d];
  const float sp = (v > 20.f) ? v : log1pf(__expf(v));
  dt[idx] = sp + 1e-4f;
}

// ======================================================================
// scan pass A: per chunk, compute P = prod(dA) and L = local final state.
// grid (256 chain-groups, NCHUNK chunks). 16 lanes per chain, n in lane.
// ======================================================================
__global__ __launch_bounds__(256) void scanA_kernel(
    const float* __restrict__ dtv, const float* __restrict__ xc,
    const float* __restrict__ dbl, const float* __restrict__ A_log,
    float* __restrict__ xzp)
{
  __shared__ float sB[CHUNK][16];
  __shared__ float sDT[CHUNK][16];
  __shared__ float sXC[CHUNK][16];

  const int tid = threadIdx.x;
  const int cl = tid >> 4;
  const int n  = tid & 15;
  const int chunk = blockIdx.y;
  const int c  = blockIdx.x * 16 + cl;
  const int b  = c >> 11;
  const int d  = c & (D_INNER - 1);
  const int d_base = (blockIdx.x * 16) & (D_INNER - 1);
  const int rowbase = b * SEQ + chunk * CHUNK;

  for (int idx = tid; idx < CHUNK * 16; idx += 256) {
    const int i = idx >> 4, j = idx & 15;
    sB[i][j] = dbl[(size_t)(rowbase + i) * 96 + 64 + j];
    const size_t off = (size_t)(rowbase + i) * D_INNER + d_base + j;
    sDT[i][j] = dtv[off];
    sXC[i][j] = xc[off];
  }
  __syncthreads();

  const float A_dn = -__expf(A_log[d * D_STATE + n]);
  float h = 0.f, P = 1.f;
  for (int i = 0; i < CHUNK; ++i) {
    const float dt_v = sDT[i][cl];
    const float xc_v = sXC[i][cl];
    const float Bn = sB[i][n];
    float t1 = dt_v * A_dn;
    t1 = fminf(fmaxf(t1, -10.f), 10.f);
    const float dA = __expf(t1);
    h = fmaf(dA, h, dt_v * Bn * xc_v);
    P *= dA;
  }
  const int idx = chunk * (BATCH * D_INNER * 16) + ((b << 11) + d) * 16 + n;
  plh_at(xzp, idx) = P;                         // P slice
  plh_at(xzp, idx + PLH_SLICE) = h;             // L slice
}

// ======================================================================
// scan pass B: chain chunk states. HST[c] = state entering chunk c.
// ======================================================================
__global__ __launch_bounds__(256) void scanB_kernel(float* __restrict__ xzp)
{
  const int t = blockIdx.x * 256 + threadIdx.x;   // 0..65535 = (b,d,n)
  float hs = 0.f;
#pragma unroll
  for (int c = 0; c < NCHUNK; ++c) {
    const int ip = c * (BATCH * D_INNER * 16) + t;
    const float P = plh_at(xzp, ip);
    const float L = plh_at(xzp, ip + PLH_SLICE);
    plh_at(xzp, ip + 2 * PLH_SLICE) = hs;       // HST slice
    hs = fmaf(P, hs, L);
  }
}

// ======================================================================
// scan pass C: per chunk full scan seeded by HST; fuses y=<h,C>, D-skip,
// SiLU(z) gate. grid (256 chain-groups, NCHUNK chunks).
// ======================================================================
__global__ __launch_bounds__(256) void scanC_kernel(
    const float* __restrict__ dtv, const float* __restrict__ xc,
    const float* __restrict__ dbl, const float* __restrict__ A_log,
    const float* __restrict__ Dp,  float* __restrict__ xzp,
    float* __restrict__ yg)
{
  __shared__ float sBC[CHUNK][32];
  __shared__ float sDT[CHUNK][16];
  __shared__ float sXC[CHUNK][16];

  const int tid = threadIdx.x;
  const int cl = tid >> 4;                     // chain-local 0..15
  const int n  = tid & 15;                     // state index
  const int chunk = blockIdx.y;
  const int c  = blockIdx.x * 16 + cl;         // global chain
  const int b  = c >> 11;
  const int d  = c & (D_INNER - 1);
  const int d_base = (blockIdx.x * 16) & (D_INNER - 1);
  const int rowbase = b * SEQ + chunk * CHUNK;

  for (int idx = tid; idx < CHUNK * 32; idx += 256) {
    const int i = idx >> 5, j = idx & 31;
    sBC[i][j] = dbl[(size_t)(rowbase + i) * 96 + 64 + j];
  }
  for (int idx = tid; idx < CHUNK * 16; idx += 256) {
    const int i = idx >> 4, j = idx & 15;
    const size_t off = (size_t)(rowbase + i) * D_INNER + d_base + j;
    sDT[i][j] = dtv[off];
    sXC[i][j] = xc[off];
  }
  __syncthreads();

  const float A_dn = -__expf(A_log[d * D_STATE + n]);
  const float Dd = Dp[d];
  const int hidx = chunk * (BATCH * D_INNER * 16) + ((b << 11) + d) * 16 + n;
  float h = plh_at(xzp, hidx + 2 * PLH_SLICE);

  for (int i = 0; i < CHUNK; ++i) {
    const float dt_v = sDT[i][cl];
    const float xc_v = sXC[i][cl];
    const float Bn = sBC[i][n];
    const float Cn = sBC[i][16 + n];
    float t1 = dt_v * A_dn;
    t1 = fminf(fmaxf(t1, -10.f), 10.f);
    const float dA = __expf(t1);
    h = fmaf(dA, h, dt_v * Bn * xc_v);
    float yp = h * Cn;
    yp += __shfl_xor(yp, 1, 16);
    yp += __shfl_xor(yp, 2, 16);
    yp += __shfl_xor(yp, 4, 16);
    yp += __shfl_xor(yp, 8, 16);
    if (n == 0) {
      const int m = rowbase + i;
      const float zv = xzp[(size_t)m * (2 * D_INNER) + D_INNER + d];
      const float sil = zv / (1.f + __expf(-zv));
      yg[(size_t)m * D_INNER + d] = (yp + xc_v * Dd) * sil;
    }
  }
}

// ======================================================================
// RMSNorm over d_inner per row, in place on yg.
// ======================================================================
__global__ __launch_bounds__(256) void rms_kernel(
    float* __restrict__ yg, const float* __restrict__ rms_w)
{
  const int m = blockIdx.x;
  float* row = yg + (size_t)m * D_INNER;
  const int e0 = threadIdx.x * 8;
  float4 v0 = *(float4*)&row[e0];
  float4 v1 = *(float4*)&row[e0 + 4];
  float ss = v0.x*v0.x + v0.y*v0.y + v0.z*v0.z + v0.w*v0.w
           + v1.x*v1.x + v1.y*v1.y + v1.z*v1.z + v1.w*v1.w;
#pragma unroll
  for (int off = 32; off > 0; off >>= 1) ss += __shfl_down(ss, off);
  __shared__ float wsum[4];
  const int lane = threadIdx.x & 63, wid = threadIdx.x >> 6;
  if (lane == 0) wsum[wid] = ss;
  __syncthreads();
  const float total = wsum[0] + wsum[1] + wsum[2] + wsum[3];
  const float scale = rsqrtf(total / (float)D_INNER + 1e-6f);
  const float4 w0 = *(const float4*)&rms_w[e0];
  const float4 w1 = *(const float4*)&rms_w[e0 + 4];
  v0.x *= scale * w0.x; v0.y *= scale * w0.y; v0.z *= scale * w0.z; v0.w *= scale * w0.w;
  v1.x *= scale * w1.x; v1.y *= scale * w1.y; v1.z *= scale * w1.z; v1.w *= scale * w1.w;
  *(float4*)&row[e0] = v0;
  *(float4*)&row[e0 + 4] = v1;
}

// ======================================================================
extern "C" void kernel_launch(void* const* d_in, const int* in_sizes, int n_in,
                              void* d_out, int out_size, void* d_ws, size_t ws_size,
                              hipStream_t stream) {
  const float* x      = (const float*)d_in[0];
  const float* W_in   = (const float*)d_in[1];
  const float* W_conv = (const float*)d_in[2];
  const float* b_conv = (const float*)d_in[3];
  const float* W_x    = (const float*)d_in[4];
  const float* W_dt   = (const float*)d_in[5];
  const float* b_dt   = (const float*)d_in[6];
  const float* A_log  = (const float*)d_in[7];
  const float* Dp     = (const float*)d_in[8];
  const float* rms_w  = (const float*)d_in[9];
  const float* W_out  = (const float*)d_in[10];
  float* out = (float*)d_out;
  float* ws  = (float*)d_ws;

  float* xz  = ws + XZ_OFF;
  float* xc  = ws + XC_OFF;
  float* dbl = ws + DBL_OFF;
  float* dt  = ws + DT_OFF;
  float* yg  = ws + YG_OFF;

  // 1. in_proj: xz = x @ W_in^T
  {
    dim3 g((2 * D_INNER) / BN, NROWS / BM);
    gemm_f32_nt<<<g, 256, 0, stream>>>(x, D_MODEL, W_in, D_MODEL, xz, 2 * D_INNER,
                                       NROWS, 2 * D_INNER, D_MODEL);
  }
  // 2. conv + silu -> xc   (consumes x_in half of xz; that half is dead afterwards)
  conv_silu_kernel<<<(NROWS * D_INNER) / 256, 256, 0, stream>>>(xz, W_conv, b_conv, xc);
  // 3. x_proj: dbl = xc @ W_x^T
  {
    dim3 g(1, NROWS / BM);
    gemm_f32_nt<<<g, 256, 0, stream>>>(xc, D_INNER, W_x, D_INNER, dbl, 96,
                                       NROWS, 96, D_INNER);
  }
  // 4. dt_proj: dt_raw = dbl[:, :64] @ W_dt^T
  {
    dim3 g(D_INNER / BN, NROWS / BM);
    gemm_f32_nt<<<g, 256, 0, stream>>>(dbl, 96, W_dt, DT_RANK, dt, D_INNER,
                                       NROWS, D_INNER, DT_RANK);
  }
  // 5. dt = softplus(dt_raw + b_dt) + 1e-4
  dt_act_kernel<<<(NROWS * D_INNER) / 256, 256, 0, stream>>>(dt, b_dt);
  // 6. chunked selective scan (A: per-chunk P/L, B: chain, C: outputs)
  {
    dim3 gA((BATCH * D_INNER) / 16, NCHUNK);
    scanA_kernel<<<gA, 256, 0, stream>>>(dt, xc, dbl, A_log, xz);
    scanB_kernel<<<(BATCH * D_INNER * 16) / 256, 256, 0, stream>>>(xz);
    dim3 gC((BATCH * D_INNER) / 16, NCHUNK);
    scanC_kernel<<<gC, 256, 0, stream>>>(dt, xc, dbl, A_log, Dp, xz, yg);
  }
  // 7. RMSNorm (in place)
  rms_kernel<<<NROWS, 256, 0, stream>>>(yg, rms_w);
  // 8. out_proj: out = yg @ W_out^T
  {
    dim3 g(D_MODEL / BN, NROWS / BM);
    gemm_f32_nt<<<g, 256, 0, stream>>>(yg, D_INNER, W_out, D_INNER, out, D_MODEL,
                                       NROWS, D_MODEL, D_INNER);
  }
}

// Round 5
// 447.692 us; speedup vs baseline: 3.3634x; 2.4227x over previous
//
#include <hip/hip_runtime.h>
#include <hip/hip_bf16.h>

// ---------------- problem dims ----------------
#define D_MODEL 1024
#define D_INNER 2048
#define D_STATE 16
#define D_CONVK 4
#define DT_RANK 64
#define BATCH   2
#define SEQ     1024
#define NROWS   (BATCH*SEQ)          // 2048 rows (b*s flattened)

// scan chunking
#define NCHUNK  16
#define CHUNK   (SEQ/NCHUNK)         // 64

// ---------------- ws layout (float elements) ----------------
#define XZ_OFF  0
#define XZ_SZ   (NROWS*2*D_INNER)
#define XC_OFF  (XZ_OFF + XZ_SZ)
#define XC_SZ   (NROWS*D_INNER)
#define DBL_OFF (XC_OFF + XC_SZ)
#define DBL_SZ  (NROWS*96)
#define DT_OFF  (DBL_OFF + DBL_SZ)
#define DT_SZ   (NROWS*D_INNER)
#define YG_OFF  (DT_OFF + DT_SZ)
#define YG_SZ   (NROWS*D_INNER)
// total = 21,168,128 floats = 84.7 MB (unchanged)
//
// Region reuse over time (write-before-read everywhere):
//  yg region  : [start] xb bf16 (1M floats) | W_in_b bf16 (2M floats)  -> dead once scanC writes yg f32
//  dt region  : [after scanC] ygb bf16 (2M floats) | W_out_b bf16 (1M floats)
//  xz x_in half: dead after conv -> P/L/HST slices (rows 0..1535)

#define PLH_SLICE (1<<20)
__device__ __forceinline__ float& plh_at(float* xz, int i) {
  return xz[((size_t)(i >> 11)) * (2 * D_INNER) + (i & (D_INNER - 1))];
}

typedef unsigned short ushort_t;
typedef __attribute__((ext_vector_type(8))) short  bf16x8;
typedef __attribute__((ext_vector_type(4))) float  f32x4;

__device__ __forceinline__ ushort_t f2bf(float f) {
  unsigned u = __float_as_uint(f);
  unsigned r = (u + 0x7fffu + ((u >> 16) & 1u)) >> 16;
  return (ushort_t)r;
}

__device__ __forceinline__ void gld_lds16(const ushort_t* g, ushort_t* l) {
  __builtin_amdgcn_global_load_lds(
      (const __attribute__((address_space(1))) unsigned int*)(const void*)g,
      (__attribute__((address_space(3))) unsigned int*)(void*)l,
      16, 0, 0);
}

// ======================================================================
// f32 -> bf16 convert (float4 in, ushort4 out)
// ======================================================================
__global__ __launch_bounds__(256) void f32_to_bf16_kernel(
    const float* __restrict__ src, ushort_t* __restrict__ dst, int n4)
{
  const int i = blockIdx.x * 256 + threadIdx.x;
  if (i >= n4) return;
  const float4 v = ((const float4*)src)[i];
  ushort4 o;
  o.x = f2bf(v.x); o.y = f2bf(v.y); o.z = f2bf(v.z); o.w = f2bf(v.w);
  ((ushort4*)dst)[i] = o;
}

// ======================================================================
// bf16 MFMA GEMM (m97 structure): C[M][N] = A[M][lda] * B[N][ldb]^T, f32 out.
// 128x128 tile, BK=32, 4 waves (2x2), 4x4 frags of 16x16x32 per wave.
// M,N multiples of 128; K multiple of 32. global_load_lds 16B staging.
// ======================================================================
__global__ __launch_bounds__(256) void gemm_bf16_nt(
    const ushort_t* __restrict__ A, int lda,
    const ushort_t* __restrict__ B, int ldb,
    float* __restrict__ C, int ldc,
    int M, int N, int K)
{
  __shared__ __attribute__((aligned(16))) ushort_t As[128 * 32];
  __shared__ __attribute__((aligned(16))) ushort_t Bs[128 * 32];

  const int tid  = threadIdx.x;
  const int wid  = tid >> 6;
  const int lane = tid & 63;
  const int wm   = wid >> 1;         // 0..1
  const int wn   = wid & 1;          // 0..1
  const int lm   = lane & 15;        // frag row/col
  const int lk   = lane >> 4;        // k-group 0..3
  const int bm   = blockIdx.y * 128;
  const int bn   = blockIdx.x * 128;

  const int srow = lane >> 2;        // 0..15 within a 16-row issue
  const int scol = (lane & 3) * 8;   // bf16 col offset {0,8,16,24}

  f32x4 acc[4][4];
#pragma unroll
  for (int i = 0; i < 4; ++i)
#pragma unroll
    for (int j = 0; j < 4; ++j) acc[i][j] = (f32x4){0.f, 0.f, 0.f, 0.f};

  for (int k0 = 0; k0 < K; k0 += 32) {
    __syncthreads();
#pragma unroll
    for (int issue = 0; issue < 2; ++issue) {
      const int r = wid * 32 + issue * 16;   // tile row base this issue
      gld_lds16(A + (size_t)(bm + r + srow) * lda + k0 + scol, &As[r * 32]);
      gld_lds16(B + (size_t)(bn + r + srow) * ldb + k0 + scol, &Bs[r * 32]);
    }
    __syncthreads();

    bf16x8 af[4], bf[4];
#pragma unroll
    for (int mi = 0; mi < 4; ++mi)
      af[mi] = *(const bf16x8*)&As[(wm * 64 + mi * 16 + lm) * 32 + lk * 8];
#pragma unroll
    for (int ni = 0; ni < 4; ++ni)
      bf[ni] = *(const bf16x8*)&Bs[(wn * 64 + ni * 16 + lm) * 32 + lk * 8];
#pragma unroll
    for (int mi = 0; mi < 4; ++mi)
#pragma unroll
      for (int ni = 0; ni < 4; ++ni)
        acc[mi][ni] = __builtin_amdgcn_mfma_f32_16x16x32_bf16(
            af[mi], bf[ni], acc[mi][ni], 0, 0, 0);
  }

#pragma unroll
  for (int mi = 0; mi < 4; ++mi) {
#pragma unroll
    for (int ni = 0; ni < 4; ++ni) {
      const f32x4 v = acc[mi][ni];
      const int row0 = bm + wm * 64 + mi * 16 + lk * 4;
      const int col  = bn + wn * 64 + ni * 16 + lm;
#pragma unroll
      for (int r = 0; r < 4; ++r)
        C[(size_t)(row0 + r) * ldc + col] = v[r];
    }
  }
}

// ======================================================================
// f32 SIMT GEMM (kept for dt_proj):  C = A * B^T
// ======================================================================
#define BM 128
#define BN 128
#define BKG 16

__global__ __launch_bounds__(256) void gemm_f32_nt(
    const float* __restrict__ A, int lda,
    const float* __restrict__ B, int ldb,
    float* __restrict__ C, int ldc,
    int M, int N, int K)
{
  __shared__ float As[BKG][BM + 4];
  __shared__ float Bs[BKG][BN + 4];

  const int tid = threadIdx.x;
  const int bm = blockIdx.y * BM;
  const int bn = blockIdx.x * BN;
  const int tm = tid >> 4;
  const int tn = tid & 15;
  const int ar = tid >> 2;
  const int ac = (tid & 3) * 4;

  float acc[8][8];
#pragma unroll
  for (int i = 0; i < 8; ++i)
#pragma unroll
    for (int j = 0; j < 8; ++j) acc[i][j] = 0.f;

  for (int k0 = 0; k0 < K; k0 += BKG) {
#pragma unroll
    for (int half = 0; half < 2; ++half) {
      const int row = ar + half * 64;
      {
        const int gm = bm + row;
        float4 v = make_float4(0.f, 0.f, 0.f, 0.f);
        if (gm < M) v = *(const float4*)(A + (size_t)gm * lda + k0 + ac);
        As[ac + 0][row] = v.x; As[ac + 1][row] = v.y;
        As[ac + 2][row] = v.z; As[ac + 3][row] = v.w;
      }
      {
        const int gn = bn + row;
        float4 v = make_float4(0.f, 0.f, 0.f, 0.f);
        if (gn < N) v = *(const float4*)(B + (size_t)gn * ldb + k0 + ac);
        Bs[ac + 0][row] = v.x; Bs[ac + 1][row] = v.y;
        Bs[ac + 2][row] = v.z; Bs[ac + 3][row] = v.w;
      }
    }
    __syncthreads();

#pragma unroll
    for (int kk = 0; kk < BKG; ++kk) {
      const float4 a0 = *(const float4*)&As[kk][tm * 8];
      const float4 a1 = *(const float4*)&As[kk][tm * 8 + 4];
      const float4 b0 = *(const float4*)&Bs[kk][tn * 8];
      const float4 b1 = *(const float4*)&Bs[kk][tn * 8 + 4];
      const float a[8] = {a0.x,a0.y,a0.z,a0.w,a1.x,a1.y,a1.z,a1.w};
      const float b[8] = {b0.x,b0.y,b0.z,b0.w,b1.x,b1.y,b1.z,b1.w};
#pragma unroll
      for (int i = 0; i < 8; ++i)
#pragma unroll
        for (int j = 0; j < 8; ++j)
          acc[i][j] = fmaf(a[i], b[j], acc[i][j]);
    }
    __syncthreads();
  }

#pragma unroll
  for (int i = 0; i < 8; ++i) {
    const int gm = bm + tm * 8 + i;
    if (gm >= M) continue;
    const int gn0 = bn + tn * 8;
    if (gn0 + 7 < N) {
      *(float4*)(C + (size_t)gm * ldc + gn0)     = make_float4(acc[i][0], acc[i][1], acc[i][2], acc[i][3]);
      *(float4*)(C + (size_t)gm * ldc + gn0 + 4) = make_float4(acc[i][4], acc[i][5], acc[i][6], acc[i][7]);
    } else {
#pragma unroll
      for (int j = 0; j < 8; ++j)
        if (gn0 + j < N) C[(size_t)gm * ldc + gn0 + j] = acc[i][j];
    }
  }
}

// ======================================================================
// x_proj split-K:  dbl[2048][96] += xc[128-tile][Kchunk] * W_x[96][Kchunk]^T
// grid (M/128, 8 K-splits); dbl must be pre-zeroed. atomicAdd f32 epilogue.
// ======================================================================
#define XSPL 8
#define XKC  (D_INNER / XSPL)   // 256

__global__ __launch_bounds__(256) void xproj_splitk_kernel(
    const float* __restrict__ A,   // xc [2048][2048]
    const float* __restrict__ B,   // W_x [96][2048]
    float* __restrict__ C)         // dbl [2048][96]
{
  __shared__ float As[BKG][BM + 4];
  __shared__ float Bs[BKG][BN + 4];

  const int tid = threadIdx.x;
  const int bm = blockIdx.x * BM;
  const int kbase = blockIdx.y * XKC;
  const int tm = tid >> 4;
  const int tn = tid & 15;
  const int ar = tid >> 2;
  const int ac = (tid & 3) * 4;

  float acc[8][8];
#pragma unroll
  for (int i = 0; i < 8; ++i)
#pragma unroll
    for (int j = 0; j < 8; ++j) acc[i][j] = 0.f;

  for (int k0 = kbase; k0 < kbase + XKC; k0 += BKG) {
#pragma unroll
    for (int half = 0; half < 2; ++half) {
      const int row = ar + half * 64;
      {
        const int gm = bm + row;
        const float4 v = *(const float4*)(A + (size_t)gm * D_INNER + k0 + ac);
        As[ac + 0][row] = v.x; As[ac + 1][row] = v.y;
        As[ac + 2][row] = v.z; As[ac + 3][row] = v.w;
      }
      {
        float4 v = make_float4(0.f, 0.f, 0.f, 0.f);
        if (row < 96) v = *(const float4*)(B + (size_t)row * D_INNER + k0 + ac);
        Bs[ac + 0][row] = v.x; Bs[ac + 1][row] = v.y;
        Bs[ac + 2][row] = v.z; Bs[ac + 3][row] = v.w;
      }
    }
    __syncthreads();

#pragma unroll
    for (int kk = 0; kk < BKG; ++kk) {
      const float4 a0 = *(const float4*)&As[kk][tm * 8];
      const float4 a1 = *(const float4*)&As[kk][tm * 8 + 4];
      const float4 b0 = *(const float4*)&Bs[kk][tn * 8];
      const float4 b1 = *(const float4*)&Bs[kk][tn * 8 + 4];
      const float a[8] = {a0.x,a0.y,a0.z,a0.w,a1.x,a1.y,a1.z,a1.w};
      const float b[8] = {b0.x,b0.y,b0.z,b0.w,b1.x,b1.y,b1.z,b1.w};
#pragma unroll
      for (int i = 0; i < 8; ++i)
#pragma unroll
        for (int j = 0; j < 8; ++j)
          acc[i][j] = fmaf(a[i], b[j], acc[i][j]);
    }
    __syncthreads();
  }

  const int gn0 = tn * 8;
  if (gn0 < 96) {
#pragma unroll
    for (int i = 0; i < 8; ++i) {
      const int gm = bm + tm * 8 + i;
#pragma unroll
      for (int j = 0; j < 8; ++j)
        if (gn0 + j < 96) atomicAdd(&C[(size_t)gm * 96 + gn0 + j], acc[i][j]);
    }
  }
}

// ======================================================================
// depthwise causal conv1d + SiLU
// ======================================================================
__global__ __launch_bounds__(256) void conv_silu_kernel(
    const float* __restrict__ xz, const float* __restrict__ Wc,
    const float* __restrict__ bc, float* __restrict__ xc)
{
  const int idx = blockIdx.x * 256 + threadIdx.x;
  const int d = idx & (D_INNER - 1);
  const int m = idx >> 11;
  const int s = m & (SEQ - 1);
  const int mb = m - s;
  float acc = bc[d];
#pragma unroll
  for (int k = 0; k < D_CONVK; ++k) {
    const int t = s + k - (D_CONVK - 1);
    if (t >= 0)
      acc = fmaf(Wc[d * D_CONVK + k], xz[(size_t)(mb + t) * (2 * D_INNER) + d], acc);
  }
  xc[idx] = acc / (1.f + __expf(-acc));
}

// ======================================================================
// dt activation (in place)
// ======================================================================
__global__ __launch_bounds__(256) void dt_act_kernel(
    float* __restrict__ dt, const float* __restrict__ b_dt)
{
  const int idx = blockIdx.x * 256 + threadIdx.x;
  const int d = idx & (D_INNER - 1);
  const float v = dt[idx] + b_dt[d];
  const float sp = (v > 20.f) ? v : log1pf(__expf(v));
  dt[idx] = sp + 1e-4f;
}

// ======================================================================
// scan pass A
// ======================================================================
__global__ __launch_bounds__(256) void scanA_kernel(
    const float* __restrict__ dtv, const float* __restrict__ xc,
    const float* __restrict__ dbl, const float* __restrict__ A_log,
    float* __restrict__ xzp)
{
  __shared__ float sB[CHUNK][16];
  __shared__ float sDT[CHUNK][16];
  __shared__ float sXC[CHUNK][16];

  const int tid = threadIdx.x;
  const int cl = tid >> 4;
  const int n  = tid & 15;
  const int chunk = blockIdx.y;
  const int c  = blockIdx.x * 16 + cl;
  const int b  = c >> 11;
  const int d  = c & (D_INNER - 1);
  const int d_base = (blockIdx.x * 16) & (D_INNER - 1);
  const int rowbase = b * SEQ + chunk * CHUNK;

  for (int idx = tid; idx < CHUNK * 16; idx += 256) {
    const int i = idx >> 4, j = idx & 15;
    sB[i][j] = dbl[(size_t)(rowbase + i) * 96 + 64 + j];
    const size_t off = (size_t)(rowbase + i) * D_INNER + d_base + j;
    sDT[i][j] = dtv[off];
    sXC[i][j] = xc[off];
  }
  __syncthreads();

  const float A_dn = -__expf(A_log[d * D_STATE + n]);
  float h = 0.f, P = 1.f;
  for (int i = 0; i < CHUNK; ++i) {
    const float dt_v = sDT[i][cl];
    const float xc_v = sXC[i][cl];
    const float Bn = sB[i][n];
    float t1 = dt_v * A_dn;
    t1 = fminf(fmaxf(t1, -10.f), 10.f);
    const float dA = __expf(t1);
    h = fmaf(dA, h, dt_v * Bn * xc_v);
    P *= dA;
  }
  const int idx = chunk * (BATCH * D_INNER * 16) + ((b << 11) + d) * 16 + n;
  plh_at(xzp, idx) = P;
  plh_at(xzp, idx + PLH_SLICE) = h;
}

// ======================================================================
// scan pass B
// ======================================================================
__global__ __launch_bounds__(256) void scanB_kernel(float* __restrict__ xzp)
{
  const int t = blockIdx.x * 256 + threadIdx.x;
  float hs = 0.f;
#pragma unroll
  for (int c = 0; c < NCHUNK; ++c) {
    const int ip = c * (BATCH * D_INNER * 16) + t;
    const float P = plh_at(xzp, ip);
    const float L = plh_at(xzp, ip + PLH_SLICE);
    plh_at(xzp, ip + 2 * PLH_SLICE) = hs;
    hs = fmaf(P, hs, L);
  }
}

// ======================================================================
// scan pass C
// ======================================================================
__global__ __launch_bounds__(256) void scanC_kernel(
    const float* __restrict__ dtv, const float* __restrict__ xc,
    const float* __restrict__ dbl, const float* __restrict__ A_log,
    const float* __restrict__ Dp,  float* __restrict__ xzp,
    float* __restrict__ yg)
{
  __shared__ float sBC[CHUNK][32];
  __shared__ float sDT[CHUNK][16];
  __shared__ float sXC[CHUNK][16];

  const int tid = threadIdx.x;
  const int cl = tid >> 4;
  const int n  = tid & 15;
  const int chunk = blockIdx.y;
  const int c  = blockIdx.x * 16 + cl;
  const int b  = c >> 11;
  const int d  = c & (D_INNER - 1);
  const int d_base = (blockIdx.x * 16) & (D_INNER - 1);
  const int rowbase = b * SEQ + chunk * CHUNK;

  for (int idx = tid; idx < CHUNK * 32; idx += 256) {
    const int i = idx >> 5, j = idx & 31;
    sBC[i][j] = dbl[(size_t)(rowbase + i) * 96 + 64 + j];
  }
  for (int idx = tid; idx < CHUNK * 16; idx += 256) {
    const int i = idx >> 4, j = idx & 15;
    const size_t off = (size_t)(rowbase + i) * D_INNER + d_base + j;
    sDT[i][j] = dtv[off];
    sXC[i][j] = xc[off];
  }
  __syncthreads();

  const float A_dn = -__expf(A_log[d * D_STATE + n]);
  const float Dd = Dp[d];
  const int hidx = chunk * (BATCH * D_INNER * 16) + ((b << 11) + d) * 16 + n;
  float h = plh_at(xzp, hidx + 2 * PLH_SLICE);

  for (int i = 0; i < CHUNK; ++i) {
    const float dt_v = sDT[i][cl];
    const float xc_v = sXC[i][cl];
    const float Bn = sBC[i][n];
    const float Cn = sBC[i][16 + n];
    float t1 = dt_v * A_dn;
    t1 = fminf(fmaxf(t1, -10.f), 10.f);
    const float dA = __expf(t1);
    h = fmaf(dA, h, dt_v * Bn * xc_v);
    float yp = h * Cn;
    yp += __shfl_xor(yp, 1, 16);
    yp += __shfl_xor(yp, 2, 16);
    yp += __shfl_xor(yp, 4, 16);
    yp += __shfl_xor(yp, 8, 16);
    if (n == 0) {
      const int m = rowbase + i;
      const float zv = xzp[(size_t)m * (2 * D_INNER) + D_INNER + d];
      const float sil = zv / (1.f + __expf(-zv));
      yg[(size_t)m * D_INNER + d] = (yp + xc_v * Dd) * sil;
    }
  }
}

// ======================================================================
// RMSNorm: read yg f32, write bf16 (for out_proj MFMA input)
// ======================================================================
__global__ __launch_bounds__(256) void rms_bf16_kernel(
    const float* __restrict__ yg, const float* __restrict__ rms_w,
    ushort_t* __restrict__ ygb)
{
  const int m = blockIdx.x;
  const float* row = yg + (size_t)m * D_INNER;
  const int e0 = threadIdx.x * 8;
  float4 v0 = *(const float4*)&row[e0];
  float4 v1 = *(const float4*)&row[e0 + 4];
  float ss = v0.x*v0.x + v0.y*v0.y + v0.z*v0.z + v0.w*v0.w
           + v1.x*v1.x + v1.y*v1.y + v1.z*v1.z + v1.w*v1.w;
#pragma unroll
  for (int off = 32; off > 0; off >>= 1) ss += __shfl_down(ss, off);
  __shared__ float wsum[4];
  const int lane = threadIdx.x & 63, wid = threadIdx.x >> 6;
  if (lane == 0) wsum[wid] = ss;
  __syncthreads();
  const float total = wsum[0] + wsum[1] + wsum[2] + wsum[3];
  const float scale = rsqrtf(total / (float)D_INNER + 1e-6f);
  const float4 w0 = *(const float4*)&rms_w[e0];
  const float4 w1 = *(const float4*)&rms_w[e0 + 4];
  ushort4 o0, o1;
  o0.x = f2bf(v0.x * scale * w0.x); o0.y = f2bf(v0.y * scale * w0.y);
  o0.z = f2bf(v0.z * scale * w0.z); o0.w = f2bf(v0.w * scale * w0.w);
  o1.x = f2bf(v1.x * scale * w1.x); o1.y = f2bf(v1.y * scale * w1.y);
  o1.z = f2bf(v1.z * scale * w1.z); o1.w = f2bf(v1.w * scale * w1.w);
  *(ushort4*)&ygb[(size_t)m * D_INNER + e0]     = o0;
  *(ushort4*)&ygb[(size_t)m * D_INNER + e0 + 4] = o1;
}

// ======================================================================
extern "C" void kernel_launch(void* const* d_in, const int* in_sizes, int n_in,
                              void* d_out, int out_size, void* d_ws, size_t ws_size,
                              hipStream_t stream) {
  const float* x      = (const float*)d_in[0];
  const float* W_in   = (const float*)d_in[1];
  const float* W_conv = (const float*)d_in[2];
  const float* b_conv = (const float*)d_in[3];
  const float* W_x    = (const float*)d_in[4];
  const float* W_dt   = (const float*)d_in[5];
  const float* b_dt   = (const float*)d_in[6];
  const float* A_log  = (const float*)d_in[7];
  const float* Dp     = (const float*)d_in[8];
  const float* rms_w  = (const float*)d_in[9];
  const float* W_out  = (const float*)d_in[10];
  float* out = (float*)d_out;
  float* ws  = (float*)d_ws;

  float* xz  = ws + XZ_OFF;
  float* xc  = ws + XC_OFF;
  float* dbl = ws + DBL_OFF;
  float* dt  = ws + DT_OFF;
  float* yg  = ws + YG_OFF;

  // bf16 staging buffers in reused regions
  ushort_t* xb      = (ushort_t*)(ws + YG_OFF);                    // 2M bf16 (1M floats)
  ushort_t* W_in_b  = (ushort_t*)(ws + YG_OFF + 1024 * 1024);      // 4M bf16 (2M floats)
  ushort_t* ygb     = (ushort_t*)(ws + DT_OFF);                    // 4M bf16 (2M floats)
  ushort_t* W_out_b = (ushort_t*)(ws + DT_OFF + 2 * 1024 * 1024);  // 2M bf16 (1M floats)

  // 0. convert x and W_in to bf16 (into yg region; dead until scanC)
  f32_to_bf16_kernel<<<(NROWS * D_MODEL / 4 + 255) / 256, 256, 0, stream>>>(x, xb, NROWS * D_MODEL / 4);
  f32_to_bf16_kernel<<<(2 * D_INNER * D_MODEL / 4 + 255) / 256, 256, 0, stream>>>(W_in, W_in_b, 2 * D_INNER * D_MODEL / 4);

  // 1. in_proj: xz = xb @ W_in_b^T   (bf16 MFMA)
  {
    dim3 g((2 * D_INNER) / 128, NROWS / 128);
    gemm_bf16_nt<<<g, 256, 0, stream>>>(xb, D_MODEL, W_in_b, D_MODEL, xz, 2 * D_INNER,
                                        NROWS, 2 * D_INNER, D_MODEL);
  }
  // 2. conv + silu -> xc
  conv_silu_kernel<<<(NROWS * D_INNER) / 256, 256, 0, stream>>>(xz, W_conv, b_conv, xc);
  // 3. x_proj: dbl = xc @ W_x^T  (split-K f32 with atomics, dbl zeroed first)
  hipMemsetAsync(dbl, 0, (size_t)NROWS * 96 * sizeof(float), stream);
  {
    dim3 g(NROWS / 128, XSPL);
    xproj_splitk_kernel<<<g, 256, 0, stream>>>(xc, W_x, dbl);
  }
  // 4. dt_proj: dt_raw = dbl[:, :64] @ W_dt^T (f32 SIMT)
  {
    dim3 g(D_INNER / BN, NROWS / BM);
    gemm_f32_nt<<<g, 256, 0, stream>>>(dbl, 96, W_dt, DT_RANK, dt, D_INNER,
                                       NROWS, D_INNER, DT_RANK);
  }
  // 5. dt = softplus(dt_raw + b_dt) + 1e-4
  dt_act_kernel<<<(NROWS * D_INNER) / 256, 256, 0, stream>>>(dt, b_dt);
  // 6. chunked selective scan
  {
    dim3 gA((BATCH * D_INNER) / 16, NCHUNK);
    scanA_kernel<<<gA, 256, 0, stream>>>(dt, xc, dbl, A_log, xz);
    scanB_kernel<<<(BATCH * D_INNER * 16) / 256, 256, 0, stream>>>(xz);
    dim3 gC((BATCH * D_INNER) / 16, NCHUNK);
    scanC_kernel<<<gC, 256, 0, stream>>>(dt, xc, dbl, A_log, Dp, xz, yg);
  }
  // 7. RMSNorm -> bf16 ygb (dt region; dt dead after scanC)
  rms_bf16_kernel<<<NROWS, 256, 0, stream>>>(yg, rms_w, ygb);
  // 7b. convert W_out -> bf16 (dt region)
  f32_to_bf16_kernel<<<(D_MODEL * D_INNER / 4 + 255) / 256, 256, 0, stream>>>(W_out, W_out_b, D_MODEL * D_INNER / 4);
  // 8. out_proj: out = ygb @ W_out_b^T  (bf16 MFMA)
  {
    dim3 g(D_MODEL / 128, NROWS / 128);
    gemm_bf16_nt<<<g, 256, 0, stream>>>(ygb, D_INNER, W_out_b, D_INNER, out, D_MODEL,
                                        NROWS, D_MODEL, D_INNER);
  }
}

// Round 6
// 321.699 us; speedup vs baseline: 4.6807x; 1.3917x over previous
//
#include <hip/hip_runtime.h>
#include <hip/hip_bf16.h>

// ---------------- problem dims ----------------
#define D_MODEL 1024
#define D_INNER 2048
#define D_STATE 16
#define D_CONVK 4
#define DT_RANK 64
#define BATCH   2
#define SEQ     1024
#define NROWS   (BATCH*SEQ)          // 2048 rows (b*s flattened)

// scan chunking (chain-per-lane layout)
#define NCHUNK  32
#define CHUNK   (SEQ/NCHUNK)         // 32

// ---------------- ws layout (float elements) ----------------
#define XZ_OFF  0
#define XZ_SZ   (NROWS*2*D_INNER)
#define XC_OFF  (XZ_OFF + XZ_SZ)
#define XC_SZ   (NROWS*D_INNER)
#define DBL_OFF (XC_OFF + XC_SZ)
#define DBL_SZ  (NROWS*96)
#define DT_OFF  (DBL_OFF + DBL_SZ)
#define DT_SZ   (NROWS*D_INNER)
#define YG_OFF  (DT_OFF + DT_SZ)
#define YG_SZ   (NROWS*D_INNER)
// total = 21,168,128 floats = 84.7 MB (unchanged)
//
// Region reuse timeline (write-before-read everywhere):
//  yg region: [t0] xb bf16 | W_in_b bf16 (dead after in_proj)
//             [scanA/B] Pbuf (2M f32) | Lbuf (2M f32) (dead after scanB)
//             [scanC] yg f32 output
//  dt region: [xproj] partials (3.07M f32) -> [dtproj] dt f32 (4M)
//             [after scanC] ygb bf16 | W_out_b bf16
//  xz x_in half (cols 0..2047): dead after conv -> HST (2M, rows 0..1023)

// HST packed into the x_in half of xz (row stride 4096)
__device__ __forceinline__ float& plh_at(float* xz, int i) {
  return xz[((size_t)(i >> 11)) * (2 * D_INNER) + (i & (D_INNER - 1))];
}

typedef unsigned short ushort_t;
typedef __attribute__((ext_vector_type(8))) short  bf16x8;
typedef __attribute__((ext_vector_type(4))) float  f32x4;

__device__ __forceinline__ ushort_t f2bf(float f) {
  unsigned u = __float_as_uint(f);
  unsigned r = (u + 0x7fffu + ((u >> 16) & 1u)) >> 16;
  return (ushort_t)r;
}

__device__ __forceinline__ void gld_lds16(const ushort_t* g, ushort_t* l) {
  __builtin_amdgcn_global_load_lds(
      (const __attribute__((address_space(1))) unsigned int*)(const void*)g,
      (__attribute__((address_space(3))) unsigned int*)(void*)l,
      16, 0, 0);
}

// ======================================================================
// f32 -> bf16 convert
// ======================================================================
__global__ __launch_bounds__(256) void f32_to_bf16_kernel(
    const float* __restrict__ src, ushort_t* __restrict__ dst, int n4)
{
  const int i = blockIdx.x * 256 + threadIdx.x;
  if (i >= n4) return;
  const float4 v = ((const float4*)src)[i];
  ushort4 o;
  o.x = f2bf(v.x); o.y = f2bf(v.y); o.z = f2bf(v.z); o.w = f2bf(v.w);
  ((ushort4*)dst)[i] = o;
}

// ======================================================================
// bf16 MFMA GEMM (m97 structure): C[M][N] = A[M][lda] * B[N][ldb]^T, f32 out.
// ======================================================================
__global__ __launch_bounds__(256) void gemm_bf16_nt(
    const ushort_t* __restrict__ A, int lda,
    const ushort_t* __restrict__ B, int ldb,
    float* __restrict__ C, int ldc,
    int M, int N, int K)
{
  __shared__ __attribute__((aligned(16))) ushort_t As[128 * 32];
  __shared__ __attribute__((aligned(16))) ushort_t Bs[128 * 32];

  const int tid  = threadIdx.x;
  const int wid  = tid >> 6;
  const int lane = tid & 63;
  const int wm   = wid >> 1;
  const int wn   = wid & 1;
  const int lm   = lane & 15;
  const int lk   = lane >> 4;
  const int bm   = blockIdx.y * 128;
  const int bn   = blockIdx.x * 128;

  const int srow = lane >> 2;
  const int scol = (lane & 3) * 8;

  f32x4 acc[4][4];
#pragma unroll
  for (int i = 0; i < 4; ++i)
#pragma unroll
    for (int j = 0; j < 4; ++j) acc[i][j] = (f32x4){0.f, 0.f, 0.f, 0.f};

  for (int k0 = 0; k0 < K; k0 += 32) {
    __syncthreads();
#pragma unroll
    for (int issue = 0; issue < 2; ++issue) {
      const int r = wid * 32 + issue * 16;
      gld_lds16(A + (size_t)(bm + r + srow) * lda + k0 + scol, &As[r * 32]);
      gld_lds16(B + (size_t)(bn + r + srow) * ldb + k0 + scol, &Bs[r * 32]);
    }
    __syncthreads();

    bf16x8 af[4], bf[4];
#pragma unroll
    for (int mi = 0; mi < 4; ++mi)
      af[mi] = *(const bf16x8*)&As[(wm * 64 + mi * 16 + lm) * 32 + lk * 8];
#pragma unroll
    for (int ni = 0; ni < 4; ++ni)
      bf[ni] = *(const bf16x8*)&Bs[(wn * 64 + ni * 16 + lm) * 32 + lk * 8];
#pragma unroll
    for (int mi = 0; mi < 4; ++mi)
#pragma unroll
      for (int ni = 0; ni < 4; ++ni)
        acc[mi][ni] = __builtin_amdgcn_mfma_f32_16x16x32_bf16(
            af[mi], bf[ni], acc[mi][ni], 0, 0, 0);
  }

#pragma unroll
  for (int mi = 0; mi < 4; ++mi) {
#pragma unroll
    for (int ni = 0; ni < 4; ++ni) {
      const f32x4 v = acc[mi][ni];
      const int row0 = bm + wm * 64 + mi * 16 + lk * 4;
      const int col  = bn + wn * 64 + ni * 16 + lm;
#pragma unroll
      for (int r = 0; r < 4; ++r)
        C[(size_t)(row0 + r) * ldc + col] = v[r];
    }
  }
}

// ======================================================================
// x_proj split-K, dense partials (no atomics):
// part[ks][m][e] = xc[m-block][k-chunk] @ W_x[e][k-chunk]^T
// BM=64 rows, 96 cols, K-chunk 128, grid (32 rowblocks, 16 splits).
// ======================================================================
#define XP_NS 16
#define XP_KC (D_INNER / XP_NS)   // 128
#define XP_BK 16

__global__ __launch_bounds__(256) void xproj_part_kernel(
    const float* __restrict__ A,   // xc [2048][2048]
    const float* __restrict__ B,   // W_x [96][2048]
    float* __restrict__ part)      // [16][2048][96]
{
  __shared__ float As[XP_BK][64 + 4];
  __shared__ float Bs[XP_BK][96 + 4];

  const int tid = threadIdx.x;
  const int bm = blockIdx.x * 64;
  const int kbase = blockIdx.y * XP_KC;
  const int tm = tid >> 4;          // 0..15 -> 4 rows each
  const int tn = tid & 15;          // 0..15 -> 6 cols each

  float acc[4][6];
#pragma unroll
  for (int i = 0; i < 4; ++i)
#pragma unroll
    for (int j = 0; j < 6; ++j) acc[i][j] = 0.f;

  for (int k0 = kbase; k0 < kbase + XP_KC; k0 += XP_BK) {
    {
      const int row = tid >> 2, kc = (tid & 3) * 4;   // 64 rows x 16 k
      const float4 v = *(const float4*)(A + (size_t)(bm + row) * D_INNER + k0 + kc);
      As[kc + 0][row] = v.x; As[kc + 1][row] = v.y;
      As[kc + 2][row] = v.z; As[kc + 3][row] = v.w;
    }
    for (int idx = tid; idx < 96 * 4; idx += 256) {   // 96 rows x 16 k
      const int row = idx >> 2, kc = (idx & 3) * 4;
      const float4 v = *(const float4*)(B + (size_t)row * D_INNER + k0 + kc);
      Bs[kc + 0][row] = v.x; Bs[kc + 1][row] = v.y;
      Bs[kc + 2][row] = v.z; Bs[kc + 3][row] = v.w;
    }
    __syncthreads();

#pragma unroll
    for (int kk = 0; kk < XP_BK; ++kk) {
      float a[4], b[6];
#pragma unroll
      for (int i = 0; i < 4; ++i) a[i] = As[kk][tm * 4 + i];
#pragma unroll
      for (int j = 0; j < 6; ++j) b[j] = Bs[kk][tn * 6 + j];
#pragma unroll
      for (int i = 0; i < 4; ++i)
#pragma unroll
        for (int j = 0; j < 6; ++j)
          acc[i][j] = fmaf(a[i], b[j], acc[i][j]);
    }
    __syncthreads();
  }

  float* p = part + (size_t)blockIdx.y * (NROWS * 96);
#pragma unroll
  for (int i = 0; i < 4; ++i) {
    const int gm = bm + tm * 4 + i;
#pragma unroll
    for (int j = 0; j < 6; ++j)
      p[(size_t)gm * 96 + tn * 6 + j] = acc[i][j];
  }
}

// dbl = sum over 16 partial slices (float4 over 2048*96)
__global__ __launch_bounds__(256) void xproj_reduce_kernel(
    const float* __restrict__ part, float* __restrict__ dbl)
{
  const int i = blockIdx.x * 256 + threadIdx.x;   // 49152 float4s
  const float4* p4 = (const float4*)part;
  float4 s = p4[i];
#pragma unroll
  for (int ks = 1; ks < XP_NS; ++ks) {
    const float4 v = p4[(size_t)ks * (NROWS * 96 / 4) + i];
    s.x += v.x; s.y += v.y; s.z += v.z; s.w += v.w;
  }
  ((float4*)dbl)[i] = s;
}

// ======================================================================
// dt_proj + fused softplus:  dt[m][d] = softplus(dbl[m][:64] @ W_dt[d]^T + b_dt[d]) + 1e-4
// 128x128 tile, K=64.
// ======================================================================
__global__ __launch_bounds__(256) void dtproj_kernel(
    const float* __restrict__ A,    // dbl [2048][96] (cols 0..63)
    const float* __restrict__ B,    // W_dt [2048][64]
    const float* __restrict__ b_dt,
    float* __restrict__ C)          // dt [2048][2048]
{
  __shared__ float As[16][128 + 4];
  __shared__ float Bs[16][128 + 4];

  const int tid = threadIdx.x;
  const int bm = blockIdx.y * 128;
  const int bn = blockIdx.x * 128;
  const int tm = tid >> 4;
  const int tn = tid & 15;

  float acc[8][8];
#pragma unroll
  for (int i = 0; i < 8; ++i)
#pragma unroll
    for (int j = 0; j < 8; ++j) acc[i][j] = 0.f;

  for (int k0 = 0; k0 < DT_RANK; k0 += 16) {
    for (int idx = tid; idx < 512; idx += 256) {
      const int row = idx >> 2, kc = (idx & 3) * 4;
      {
        const float4 v = *(const float4*)(A + (size_t)(bm + row) * 96 + k0 + kc);
        As[kc + 0][row] = v.x; As[kc + 1][row] = v.y;
        As[kc + 2][row] = v.z; As[kc + 3][row] = v.w;
      }
      {
        const float4 v = *(const float4*)(B + (size_t)(bn + row) * DT_RANK + k0 + kc);
        Bs[kc + 0][row] = v.x; Bs[kc + 1][row] = v.y;
        Bs[kc + 2][row] = v.z; Bs[kc + 3][row] = v.w;
      }
    }
    __syncthreads();

#pragma unroll
    for (int kk = 0; kk < 16; ++kk) {
      const float4 a0 = *(const float4*)&As[kk][tm * 8];
      const float4 a1 = *(const float4*)&As[kk][tm * 8 + 4];
      const float4 b0 = *(const float4*)&Bs[kk][tn * 8];
      const float4 b1 = *(const float4*)&Bs[kk][tn * 8 + 4];
      const float a[8] = {a0.x,a0.y,a0.z,a0.w,a1.x,a1.y,a1.z,a1.w};
      const float b[8] = {b0.x,b0.y,b0.z,b0.w,b1.x,b1.y,b1.z,b1.w};
#pragma unroll
      for (int i = 0; i < 8; ++i)
#pragma unroll
        for (int j = 0; j < 8; ++j)
          acc[i][j] = fmaf(a[i], b[j], acc[i][j]);
    }
    __syncthreads();
  }

  const int gn0 = bn + tn * 8;
  float bv[8];
#pragma unroll
  for (int j = 0; j < 8; ++j) bv[j] = b_dt[gn0 + j];
#pragma unroll
  for (int i = 0; i < 8; ++i) {
    const int gm = bm + tm * 8 + i;
    float o[8];
#pragma unroll
    for (int j = 0; j < 8; ++j) {
      const float v = acc[i][j] + bv[j];
      const float sp = (v > 20.f) ? v : log1pf(__expf(v));
      o[j] = sp + 1e-4f;
    }
    *(float4*)(C + (size_t)gm * D_INNER + gn0)     = make_float4(o[0], o[1], o[2], o[3]);
    *(float4*)(C + (size_t)gm * D_INNER + gn0 + 4) = make_float4(o[4], o[5], o[6], o[7]);
  }
}

// ======================================================================
// depthwise causal conv1d + SiLU
// ======================================================================
__global__ __launch_bounds__(256) void conv_silu_kernel(
    const float* __restrict__ xz, const float* __restrict__ Wc,
    const float* __restrict__ bc, float* __restrict__ xc)
{
  const int idx = blockIdx.x * 256 + threadIdx.x;
  const int d = idx & (D_INNER - 1);
  const int m = idx >> 11;
  const int s = m & (SEQ - 1);
  const int mb = m - s;
  float acc = bc[d];
#pragma unroll
  for (int k = 0; k < D_CONVK; ++k) {
    const int t = s + k - (D_CONVK - 1);
    if (t >= 0)
      acc = fmaf(Wc[d * D_CONVK + k], xz[(size_t)(mb + t) * (2 * D_INNER) + d], acc);
  }
  xc[idx] = acc / (1.f + __expf(-acc));
}

// ======================================================================
// scan pass A (chain-per-lane): lane owns chain (b,d,chunk); h[16],P[16] in regs.
// grid (D_INNER/256, NCHUNK, BATCH). Writes P,L at [chunk][b][n][d].
// ======================================================================
__global__ __launch_bounds__(256) void scanA_kernel(
    const float* __restrict__ dtv, const float* __restrict__ xc,
    const float* __restrict__ dbl, const float* __restrict__ A_log,
    float* __restrict__ Pbuf, float* __restrict__ Lbuf)
{
  __shared__ float sB[CHUNK][16];

  const int tid = threadIdx.x;
  const int d = blockIdx.x * 256 + tid;
  const int chunk = blockIdx.y;
  const int b = blockIdx.z;
  const int rowbase = b * SEQ + chunk * CHUNK;

  for (int idx = tid; idx < CHUNK * 16; idx += 256) {
    const int i = idx >> 4, n = idx & 15;
    sB[i][n] = dbl[(size_t)(rowbase + i) * 96 + 64 + n];
  }

  float A_d[16];
#pragma unroll
  for (int j = 0; j < 4; ++j) {
    const float4 va = *(const float4*)&A_log[d * D_STATE + j * 4];
    A_d[j * 4 + 0] = -__expf(va.x);
    A_d[j * 4 + 1] = -__expf(va.y);
    A_d[j * 4 + 2] = -__expf(va.z);
    A_d[j * 4 + 3] = -__expf(va.w);
  }
  __syncthreads();

  float h[16], P[16];
#pragma unroll
  for (int n = 0; n < 16; ++n) { h[n] = 0.f; P[n] = 1.f; }

  for (int i = 0; i < CHUNK; ++i) {
    const size_t off = (size_t)(rowbase + i) * D_INNER + d;
    const float dt_v = dtv[off];
    const float dtxc = dt_v * xc[off];
    const float4 B0 = *(const float4*)&sB[i][0];
    const float4 B1 = *(const float4*)&sB[i][4];
    const float4 B2 = *(const float4*)&sB[i][8];
    const float4 B3 = *(const float4*)&sB[i][12];
    const float Bv[16] = {B0.x,B0.y,B0.z,B0.w, B1.x,B1.y,B1.z,B1.w,
                          B2.x,B2.y,B2.z,B2.w, B3.x,B3.y,B3.z,B3.w};
#pragma unroll
    for (int n = 0; n < 16; ++n) {
      float t = dt_v * A_d[n];
      t = fminf(fmaxf(t, -10.f), 10.f);
      const float dA = __expf(t);
      h[n] = fmaf(dA, h[n], dtxc * Bv[n]);
      P[n] *= dA;
    }
  }

  const size_t base = ((size_t)(chunk * BATCH + b) * 16) * D_INNER + d;
#pragma unroll
  for (int n = 0; n < 16; ++n) {
    Pbuf[base + (size_t)n * D_INNER] = P[n];
    Lbuf[base + (size_t)n * D_INNER] = h[n];
  }
}

// ======================================================================
// scan pass B: chain chunk states; HST[c] = state entering chunk c.
// threads = (b,n,d) = 65536.
// ======================================================================
__global__ __launch_bounds__(256) void scanB_kernel(
    const float* __restrict__ Pbuf, const float* __restrict__ Lbuf,
    float* __restrict__ xzp)
{
  const int t = blockIdx.x * 256 + threadIdx.x;
  const int d = t & (D_INNER - 1);
  const int n = (t >> 11) & 15;
  const int b = t >> 15;
  float hs = 0.f;
#pragma unroll
  for (int c = 0; c < NCHUNK; ++c) {
    const int idx = ((c * BATCH + b) * 16 + n) * D_INNER + d;
    plh_at(xzp, idx) = hs;
    hs = fmaf(Pbuf[idx], hs, Lbuf[idx]);
  }
}

// ======================================================================
// scan pass C (chain-per-lane): seeded by HST, fuses y, D-skip, SiLU(z) gate.
// grid (D_INNER/256, NCHUNK, BATCH). Writes yg (over Pbuf/Lbuf region).
// ======================================================================
__global__ __launch_bounds__(256) void scanC_kernel(
    const float* __restrict__ dtv, const float* __restrict__ xc,
    const float* __restrict__ dbl, const float* __restrict__ A_log,
    const float* __restrict__ Dp,  float* __restrict__ xzp,
    float* __restrict__ yg)
{
  __shared__ float sBC[CHUNK][32];

  const int tid = threadIdx.x;
  const int d = blockIdx.x * 256 + tid;
  const int chunk = blockIdx.y;
  const int b = blockIdx.z;
  const int rowbase = b * SEQ + chunk * CHUNK;

  for (int idx = tid; idx < CHUNK * 32; idx += 256) {
    const int i = idx >> 5, j = idx & 31;
    sBC[i][j] = dbl[(size_t)(rowbase + i) * 96 + 64 + j];
  }

  float A_d[16];
#pragma unroll
  for (int j = 0; j < 4; ++j) {
    const float4 va = *(const float4*)&A_log[d * D_STATE + j * 4];
    A_d[j * 4 + 0] = -__expf(va.x);
    A_d[j * 4 + 1] = -__expf(va.y);
    A_d[j * 4 + 2] = -__expf(va.z);
    A_d[j * 4 + 3] = -__expf(va.w);
  }
  const float Dd = Dp[d];
  __syncthreads();

  float h[16];
  {
    const int hbase = ((chunk * BATCH + b) * 16) * D_INNER + d;
#pragma unroll
    for (int n = 0; n < 16; ++n) h[n] = plh_at(xzp, hbase + n * D_INNER);
  }

  for (int i = 0; i < CHUNK; ++i) {
    const int m = rowbase + i;
    const size_t off = (size_t)m * D_INNER + d;
    const float dt_v = dtv[off];
    const float xc_v = xc[off];
    const float dtxc = dt_v * xc_v;
    const float4 B0 = *(const float4*)&sBC[i][0];
    const float4 B1 = *(const float4*)&sBC[i][4];
    const float4 B2 = *(const float4*)&sBC[i][8];
    const float4 B3 = *(const float4*)&sBC[i][12];
    const float4 C0 = *(const float4*)&sBC[i][16];
    const float4 C1 = *(const float4*)&sBC[i][20];
    const float4 C2 = *(const float4*)&sBC[i][24];
    const float4 C3 = *(const float4*)&sBC[i][28];
    const float Bv[16] = {B0.x,B0.y,B0.z,B0.w, B1.x,B1.y,B1.z,B1.w,
                          B2.x,B2.y,B2.z,B2.w, B3.x,B3.y,B3.z,B3.w};
    const float Cv[16] = {C0.x,C0.y,C0.z,C0.w, C1.x,C1.y,C1.z,C1.w,
                          C2.x,C2.y,C2.z,C2.w, C3.x,C3.y,C3.z,C3.w};
    float y = 0.f;
#pragma unroll
    for (int n = 0; n < 16; ++n) {
      float t = dt_v * A_d[n];
      t = fminf(fmaxf(t, -10.f), 10.f);
      const float dA = __expf(t);
      h[n] = fmaf(dA, h[n], dtxc * Bv[n]);
      y = fmaf(h[n], Cv[n], y);
    }
    const float zv = xzp[(size_t)m * (2 * D_INNER) + D_INNER + d];
    const float sil = zv / (1.f + __expf(-zv));
    yg[off] = (y + xc_v * Dd) * sil;
  }
}

// ======================================================================
// RMSNorm: read yg f32, write bf16
// ======================================================================
__global__ __launch_bounds__(256) void rms_bf16_kernel(
    const float* __restrict__ yg, const float* __restrict__ rms_w,
    ushort_t* __restrict__ ygb)
{
  const int m = blockIdx.x;
  const float* row = yg + (size_t)m * D_INNER;
  const int e0 = threadIdx.x * 8;
  float4 v0 = *(const float4*)&row[e0];
  float4 v1 = *(const float4*)&row[e0 + 4];
  float ss = v0.x*v0.x + v0.y*v0.y + v0.z*v0.z + v0.w*v0.w
           + v1.x*v1.x + v1.y*v1.y + v1.z*v1.z + v1.w*v1.w;
#pragma unroll
  for (int off = 32; off > 0; off >>= 1) ss += __shfl_down(ss, off);
  __shared__ float wsum[4];
  const int lane = threadIdx.x & 63, wid = threadIdx.x >> 6;
  if (lane == 0) wsum[wid] = ss;
  __syncthreads();
  const float total = wsum[0] + wsum[1] + wsum[2] + wsum[3];
  const float scale = rsqrtf(total / (float)D_INNER + 1e-6f);
  const float4 w0 = *(const float4*)&rms_w[e0];
  const float4 w1 = *(const float4*)&rms_w[e0 + 4];
  ushort4 o0, o1;
  o0.x = f2bf(v0.x * scale * w0.x); o0.y = f2bf(v0.y * scale * w0.y);
  o0.z = f2bf(v0.z * scale * w0.z); o0.w = f2bf(v0.w * scale * w0.w);
  o1.x = f2bf(v1.x * scale * w1.x); o1.y = f2bf(v1.y * scale * w1.y);
  o1.z = f2bf(v1.z * scale * w1.z); o1.w = f2bf(v1.w * scale * w1.w);
  *(ushort4*)&ygb[(size_t)m * D_INNER + e0]     = o0;
  *(ushort4*)&ygb[(size_t)m * D_INNER + e0 + 4] = o1;
}

// ======================================================================
extern "C" void kernel_launch(void* const* d_in, const int* in_sizes, int n_in,
                              void* d_out, int out_size, void* d_ws, size_t ws_size,
                              hipStream_t stream) {
  const float* x      = (const float*)d_in[0];
  const float* W_in   = (const float*)d_in[1];
  const float* W_conv = (const float*)d_in[2];
  const float* b_conv = (const float*)d_in[3];
  const float* W_x    = (const float*)d_in[4];
  const float* W_dt   = (const float*)d_in[5];
  const float* b_dt   = (const float*)d_in[6];
  const float* A_log  = (const float*)d_in[7];
  const float* Dp     = (const float*)d_in[8];
  const float* rms_w  = (const float*)d_in[9];
  const float* W_out  = (const float*)d_in[10];
  float* out = (float*)d_out;
  float* ws  = (float*)d_ws;

  float* xz  = ws + XZ_OFF;
  float* xc  = ws + XC_OFF;
  float* dbl = ws + DBL_OFF;
  float* dt  = ws + DT_OFF;
  float* yg  = ws + YG_OFF;

  // region-reuse aliases
  ushort_t* xb      = (ushort_t*)(ws + YG_OFF);                    // bf16 x
  ushort_t* W_in_b  = (ushort_t*)(ws + YG_OFF + 1024 * 1024);      // bf16 W_in
  float*    xpart   = ws + DT_OFF;                                 // xproj partials (3.07M)
  float*    Pbuf    = ws + YG_OFF;                                 // scan P (2M)
  float*    Lbuf    = ws + YG_OFF + 2 * 1024 * 1024;               // scan L (2M)
  ushort_t* ygb     = (ushort_t*)(ws + DT_OFF);                    // bf16 y (post-scan)
  ushort_t* W_out_b = (ushort_t*)(ws + DT_OFF + 2 * 1024 * 1024);  // bf16 W_out

  // 0. convert x, W_in to bf16
  f32_to_bf16_kernel<<<(NROWS * D_MODEL / 4 + 255) / 256, 256, 0, stream>>>(x, xb, NROWS * D_MODEL / 4);
  f32_to_bf16_kernel<<<(2 * D_INNER * D_MODEL / 4 + 255) / 256, 256, 0, stream>>>(W_in, W_in_b, 2 * D_INNER * D_MODEL / 4);

  // 1. in_proj: xz = xb @ W_in_b^T (bf16 MFMA)
  {
    dim3 g((2 * D_INNER) / 128, NROWS / 128);
    gemm_bf16_nt<<<g, 256, 0, stream>>>(xb, D_MODEL, W_in_b, D_MODEL, xz, 2 * D_INNER,
                                        NROWS, 2 * D_INNER, D_MODEL);
  }
  // 2. conv + silu -> xc
  conv_silu_kernel<<<(NROWS * D_INNER) / 256, 256, 0, stream>>>(xz, W_conv, b_conv, xc);
  // 3. x_proj: dense split-K partials + reduce
  {
    dim3 g(NROWS / 64, XP_NS);
    xproj_part_kernel<<<g, 256, 0, stream>>>(xc, W_x, xpart);
    xproj_reduce_kernel<<<(NROWS * 96 / 4) / 256, 256, 0, stream>>>(xpart, dbl);
  }
  // 4. dt_proj + fused softplus -> dt
  {
    dim3 g(D_INNER / 128, NROWS / 128);
    dtproj_kernel<<<g, 256, 0, stream>>>(dbl, W_dt, b_dt, dt);
  }
  // 5. chunked selective scan (chain-per-lane)
  {
    dim3 gAC(D_INNER / 256, NCHUNK, BATCH);
    scanA_kernel<<<gAC, 256, 0, stream>>>(dt, xc, dbl, A_log, Pbuf, Lbuf);
    scanB_kernel<<<(BATCH * D_INNER * 16) / 256, 256, 0, stream>>>(Pbuf, Lbuf, xz);
    scanC_kernel<<<gAC, 256, 0, stream>>>(dt, xc, dbl, A_log, Dp, xz, yg);
  }
  // 6. RMSNorm -> bf16 ygb
  rms_bf16_kernel<<<NROWS, 256, 0, stream>>>(yg, rms_w, ygb);
  // 6b. convert W_out -> bf16
  f32_to_bf16_kernel<<<(D_MODEL * D_INNER / 4 + 255) / 256, 256, 0, stream>>>(W_out, W_out_b, D_MODEL * D_INNER / 4);
  // 7. out_proj: out = ygb @ W_out_b^T (bf16 MFMA)
  {
    dim3 g(D_MODEL / 128, NROWS / 128);
    gemm_bf16_nt<<<g, 256, 0, stream>>>(ygb, D_INNER, W_out_b, D_INNER, out, D_MODEL,
                                        NROWS, D_MODEL, D_INNER);
  }
}

// Round 10
// 303.339 us; speedup vs baseline: 4.9640x; 1.0605x over previous
//
#include <hip/hip_runtime.h>
#include <hip/hip_bf16.h>

// ---------------- problem dims ----------------
#define D_MODEL 1024
#define D_INNER 2048
#define D_STATE 16
#define D_CONVK 4
#define DT_RANK 64
#define BATCH   2
#define SEQ     1024
#define NROWS   (BATCH*SEQ)          // 2048 rows (b*s flattened)

// scan chunking (chain-per-lane layout)
#define NCHUNK  32
#define CHUNK   (SEQ/NCHUNK)         // 32

// ---------------- ws layout (float elements) ----------------
#define XZ_OFF  0
#define XZ_SZ   (NROWS*2*D_INNER)
#define XC_OFF  (XZ_OFF + XZ_SZ)
#define XC_SZ   (NROWS*D_INNER)
#define DBL_OFF (XC_OFF + XC_SZ)
#define DBL_SZ  (NROWS*96)
#define DT_OFF  (DBL_OFF + DBL_SZ)
#define DT_SZ   (NROWS*D_INNER)
#define YG_OFF  (DT_OFF + DT_SZ)
#define YG_SZ   (NROWS*D_INNER)
// total = 21,168,128 floats = 84.7 MB (unchanged)
//
// Region reuse timeline (write-before-read everywhere):
//  yg region: [t0] xb bf16 | W_in_b bf16 (dead after in_proj)
//             [scanA/B] Pbuf | Lbuf (dead after scanB) -> [scanC] yg f32
//  dt region: [xproj] partials -> [dtproj] dt f32
//             [after scanC] ygb bf16 | W_out_b bf16
//  xc region: conv output; dead after scanC -> out_proj split-K partials (2x2M)
//  xz x_in half: dead after conv -> HST

// HST packed into the x_in half of xz (row stride 4096)
__device__ __forceinline__ float& plh_at(float* xz, int i) {
  return xz[((size_t)(i >> 11)) * (2 * D_INNER) + (i & (D_INNER - 1))];
}

typedef unsigned short ushort_t;
typedef __attribute__((ext_vector_type(8))) short  bf16x8;
typedef __attribute__((ext_vector_type(4))) float  f32x4;

__device__ __forceinline__ ushort_t f2bf(float f) {
  unsigned u = __float_as_uint(f);
  unsigned r = (u + 0x7fffu + ((u >> 16) & 1u)) >> 16;
  return (ushort_t)r;
}

__device__ __forceinline__ void gld_lds16(const ushort_t* g, ushort_t* l) {
  __builtin_amdgcn_global_load_lds(
      (const __attribute__((address_space(1))) unsigned int*)(const void*)g,
      (__attribute__((address_space(3))) unsigned int*)(void*)l,
      16, 0, 0);
}

// ======================================================================
// f32 -> bf16 convert
// ======================================================================
__global__ __launch_bounds__(256) void f32_to_bf16_kernel(
    const float* __restrict__ src, ushort_t* __restrict__ dst, int n4)
{
  const int i = blockIdx.x * 256 + threadIdx.x;
  if (i >= n4) return;
  const float4 v = ((const float4*)src)[i];
  ushort4 o;
  o.x = f2bf(v.x); o.y = f2bf(v.y); o.z = f2bf(v.z); o.w = f2bf(v.w);
  ((ushort4*)dst)[i] = o;
}

// ======================================================================
// Single-wave bf16 MFMA GEMM: one 64-thread wave per block owns a 64x64
// output tile (4x4 frags of 16x16x32). BK=32, global_load_lds staging with
// bank-conflict swizzle (linear LDS dest, pre-swizzled global source:
// store slot s^((row>>1)&3); read slot lk^((lm>>1)&3) -> 2-way, free).
// Independent waves: no inter-wave lock-step; vmcnt drains hidden by TLP.
// Optional split-K via blockIdx.z: C slice z at C + z*M*ldc.
// ======================================================================
__global__ __launch_bounds__(64, 4) void gemm_bf16_wave(
    const ushort_t* __restrict__ A, int lda,
    const ushort_t* __restrict__ B, int ldb,
    float* __restrict__ C, int ldc, int klen)
{
  __shared__ __attribute__((aligned(16))) ushort_t As[64 * 32];
  __shared__ __attribute__((aligned(16))) ushort_t Bs[64 * 32];

  const int l  = threadIdx.x;
  const int lm = l & 15;             // frag row/col
  const int lk = l >> 4;             // k-group 0..3
  const int bn = blockIdx.x * 64;
  const int bm = blockIdx.y * 64;
  const int kbase = blockIdx.z * klen;
  float* Cz = C + (size_t)blockIdx.z * (size_t)gridDim.y * 64 * ldc;

  const int srow  = l >> 2;                          // staging row 0..15/issue
  const int scol  = ((l & 3) ^ ((l >> 3) & 3)) * 8;  // pre-swizzled source col
  const int rslot = (lk ^ ((lm >> 1) & 3)) * 8;      // swizzled read slot

  f32x4 acc[4][4];
#pragma unroll
  for (int i = 0; i < 4; ++i)
#pragma unroll
    for (int j = 0; j < 4; ++j) acc[i][j] = (f32x4){0.f, 0.f, 0.f, 0.f};

  for (int k0 = kbase; k0 < kbase + klen; k0 += 32) {
    __syncthreads();   // 1-wave: lgkm drain so prior ds_reads precede overwrite
#pragma unroll
    for (int i = 0; i < 4; ++i)
      gld_lds16(A + (size_t)(bm + i * 16 + srow) * lda + k0 + scol, &As[i * 16 * 32]);
#pragma unroll
    for (int i = 0; i < 4; ++i)
      gld_lds16(B + (size_t)(bn + i * 16 + srow) * ldb + k0 + scol, &Bs[i * 16 * 32]);
    __syncthreads();   // vmcnt drain: staged data visible

    bf16x8 af[4], bf[4];
#pragma unroll
    for (int mi = 0; mi < 4; ++mi)
      af[mi] = *(const bf16x8*)&As[(mi * 16 + lm) * 32 + rslot];
#pragma unroll
    for (int ni = 0; ni < 4; ++ni)
      bf[ni] = *(const bf16x8*)&Bs[(ni * 16 + lm) * 32 + rslot];
#pragma unroll
    for (int mi = 0; mi < 4; ++mi)
#pragma unroll
      for (int ni = 0; ni < 4; ++ni)
        acc[mi][ni] = __builtin_amdgcn_mfma_f32_16x16x32_bf16(
            af[mi], bf[ni], acc[mi][ni], 0, 0, 0);
  }

#pragma unroll
  for (int mi = 0; mi < 4; ++mi) {
#pragma unroll
    for (int ni = 0; ni < 4; ++ni) {
      const f32x4 v = acc[mi][ni];
      const int row0 = bm + mi * 16 + lk * 4;
      const int col  = bn + ni * 16 + lm;
#pragma unroll
      for (int r = 0; r < 4; ++r)
        Cz[(size_t)(row0 + r) * ldc + col] = v[r];
    }
  }
}

// out = p0 + p1 over NROWS*D_MODEL (split-K=2 reduce for out_proj)
__global__ __launch_bounds__(256) void splitk2_reduce_kernel(
    const float* __restrict__ part, float* __restrict__ out)
{
  const int i = blockIdx.x * 256 + threadIdx.x;   // over NROWS*D_MODEL/4
  const float4 a = ((const float4*)part)[i];
  const float4 b = ((const float4*)part)[i + (NROWS * D_MODEL / 4)];
  ((float4*)out)[i] = make_float4(a.x + b.x, a.y + b.y, a.z + b.z, a.w + b.w);
}

// ======================================================================
// x_proj split-K, dense partials (no atomics)
// ======================================================================
#define XP_NS 16
#define XP_KC (D_INNER / XP_NS)   // 128
#define XP_BK 16

__global__ __launch_bounds__(256) void xproj_part_kernel(
    const float* __restrict__ A,   // xc [2048][2048]
    const float* __restrict__ B,   // W_x [96][2048]
    float* __restrict__ part)      // [16][2048][96]
{
  __shared__ float As[XP_BK][64 + 4];
  __shared__ float Bs[XP_BK][96 + 4];

  const int tid = threadIdx.x;
  const int bm = blockIdx.x * 64;
  const int kbase = blockIdx.y * XP_KC;
  const int tm = tid >> 4;
  const int tn = tid & 15;

  float acc[4][6];
#pragma unroll
  for (int i = 0; i < 4; ++i)
#pragma unroll
    for (int j = 0; j < 6; ++j) acc[i][j] = 0.f;

  for (int k0 = kbase; k0 < kbase + XP_KC; k0 += XP_BK) {
    {
      const int row = tid >> 2, kc = (tid & 3) * 4;
      const float4 v = *(const float4*)(A + (size_t)(bm + row) * D_INNER + k0 + kc);
      As[kc + 0][row] = v.x; As[kc + 1][row] = v.y;
      As[kc + 2][row] = v.z; As[kc + 3][row] = v.w;
    }
    for (int idx = tid; idx < 96 * 4; idx += 256) {
      const int row = idx >> 2, kc = (idx & 3) * 4;
      const float4 v = *(const float4*)(B + (size_t)row * D_INNER + k0 + kc);
      Bs[kc + 0][row] = v.x; Bs[kc + 1][row] = v.y;
      Bs[kc + 2][row] = v.z; Bs[kc + 3][row] = v.w;
    }
    __syncthreads();

#pragma unroll
    for (int kk = 0; kk < XP_BK; ++kk) {
      float a[4], b[6];
#pragma unroll
      for (int i = 0; i < 4; ++i) a[i] = As[kk][tm * 4 + i];
#pragma unroll
      for (int j = 0; j < 6; ++j) b[j] = Bs[kk][tn * 6 + j];
#pragma unroll
      for (int i = 0; i < 4; ++i)
#pragma unroll
        for (int j = 0; j < 6; ++j)
          acc[i][j] = fmaf(a[i], b[j], acc[i][j]);
    }
    __syncthreads();
  }

  float* p = part + (size_t)blockIdx.y * (NROWS * 96);
#pragma unroll
  for (int i = 0; i < 4; ++i) {
    const int gm = bm + tm * 4 + i;
#pragma unroll
    for (int j = 0; j < 6; ++j)
      p[(size_t)gm * 96 + tn * 6 + j] = acc[i][j];
  }
}

__global__ __launch_bounds__(256) void xproj_reduce_kernel(
    const float* __restrict__ part, float* __restrict__ dbl)
{
  const int i = blockIdx.x * 256 + threadIdx.x;
  const float4* p4 = (const float4*)part;
  float4 s = p4[i];
#pragma unroll
  for (int ks = 1; ks < XP_NS; ++ks) {
    const float4 v = p4[(size_t)ks * (NROWS * 96 / 4) + i];
    s.x += v.x; s.y += v.y; s.z += v.z; s.w += v.w;
  }
  ((float4*)dbl)[i] = s;
}

// ======================================================================
// dt_proj + fused softplus
// ======================================================================
__global__ __launch_bounds__(256) void dtproj_kernel(
    const float* __restrict__ A,    // dbl [2048][96] (cols 0..63)
    const float* __restrict__ B,    // W_dt [2048][64]
    const float* __restrict__ b_dt,
    float* __restrict__ C)          // dt [2048][2048]
{
  __shared__ float As[16][128 + 4];
  __shared__ float Bs[16][128 + 4];

  const int tid = threadIdx.x;
  const int bm = blockIdx.y * 128;
  const int bn = blockIdx.x * 128;
  const int tm = tid >> 4;
  const int tn = tid & 15;

  float acc[8][8];
#pragma unroll
  for (int i = 0; i < 8; ++i)
#pragma unroll
    for (int j = 0; j < 8; ++j) acc[i][j] = 0.f;

  for (int k0 = 0; k0 < DT_RANK; k0 += 16) {
    for (int idx = tid; idx < 512; idx += 256) {
      const int row = idx >> 2, kc = (idx & 3) * 4;
      {
        const float4 v = *(const float4*)(A + (size_t)(bm + row) * 96 + k0 + kc);
        As[kc + 0][row] = v.x; As[kc + 1][row] = v.y;
        As[kc + 2][row] = v.z; As[kc + 3][row] = v.w;
      }
      {
        const float4 v = *(const float4*)(B + (size_t)(bn + row) * DT_RANK + k0 + kc);
        Bs[kc + 0][row] = v.x; Bs[kc + 1][row] = v.y;
        Bs[kc + 2][row] = v.z; Bs[kc + 3][row] = v.w;
      }
    }
    __syncthreads();

#pragma unroll
    for (int kk = 0; kk < 16; ++kk) {
      const float4 a0 = *(const float4*)&As[kk][tm * 8];
      const float4 a1 = *(const float4*)&As[kk][tm * 8 + 4];
      const float4 b0 = *(const float4*)&Bs[kk][tn * 8];
      const float4 b1 = *(const float4*)&Bs[kk][tn * 8 + 4];
      const float a[8] = {a0.x,a0.y,a0.z,a0.w,a1.x,a1.y,a1.z,a1.w};
      const float b[8] = {b0.x,b0.y,b0.z,b0.w,b1.x,b1.y,b1.z,b1.w};
#pragma unroll
      for (int i = 0; i < 8; ++i)
#pragma unroll
        for (int j = 0; j < 8; ++j)
          acc[i][j] = fmaf(a[i], b[j], acc[i][j]);
    }
    __syncthreads();
  }

  const int gn0 = bn + tn * 8;
  float bv[8];
#pragma unroll
  for (int j = 0; j < 8; ++j) bv[j] = b_dt[gn0 + j];
#pragma unroll
  for (int i = 0; i < 8; ++i) {
    const int gm = bm + tm * 8 + i;
    float o[8];
#pragma unroll
    for (int j = 0; j < 8; ++j) {
      const float v = acc[i][j] + bv[j];
      const float sp = (v > 20.f) ? v : log1pf(__expf(v));
      o[j] = sp + 1e-4f;
    }
    *(float4*)(C + (size_t)gm * D_INNER + gn0)     = make_float4(o[0], o[1], o[2], o[3]);
    *(float4*)(C + (size_t)gm * D_INNER + gn0 + 4) = make_float4(o[4], o[5], o[6], o[7]);
  }
}

// ======================================================================
// depthwise causal conv1d + SiLU
// ======================================================================
__global__ __launch_bounds__(256) void conv_silu_kernel(
    const float* __restrict__ xz, const float* __restrict__ Wc,
    const float* __restrict__ bc, float* __restrict__ xc)
{
  const int idx = blockIdx.x * 256 + threadIdx.x;
  const int d = idx & (D_INNER - 1);
  const int m = idx >> 11;
  const int s = m & (SEQ - 1);
  const int mb = m - s;
  float acc = bc[d];
#pragma unroll
  for (int k = 0; k < D_CONVK; ++k) {
    const int t = s + k - (D_CONVK - 1);
    if (t >= 0)
      acc = fmaf(Wc[d * D_CONVK + k], xz[(size_t)(mb + t) * (2 * D_INNER) + d], acc);
  }
  xc[idx] = acc / (1.f + __expf(-acc));
}

// ======================================================================
// scan pass A (chain-per-lane)
// ======================================================================
__global__ __launch_bounds__(256) void scanA_kernel(
    const float* __restrict__ dtv, const float* __restrict__ xc,
    const float* __restrict__ dbl, const float* __restrict__ A_log,
    float* __restrict__ Pbuf, float* __restrict__ Lbuf)
{
  __shared__ float sB[CHUNK][16];

  const int tid = threadIdx.x;
  const int d = blockIdx.x * 256 + tid;
  const int chunk = blockIdx.y;
  const int b = blockIdx.z;
  const int rowbase = b * SEQ + chunk * CHUNK;

  for (int idx = tid; idx < CHUNK * 16; idx += 256) {
    const int i = idx >> 4, n = idx & 15;
    sB[i][n] = dbl[(size_t)(rowbase + i) * 96 + 64 + n];
  }

  float A_d[16];
#pragma unroll
  for (int j = 0; j < 4; ++j) {
    const float4 va = *(const float4*)&A_log[d * D_STATE + j * 4];
    A_d[j * 4 + 0] = -__expf(va.x);
    A_d[j * 4 + 1] = -__expf(va.y);
    A_d[j * 4 + 2] = -__expf(va.z);
    A_d[j * 4 + 3] = -__expf(va.w);
  }
  __syncthreads();

  float h[16], P[16];
#pragma unroll
  for (int n = 0; n < 16; ++n) { h[n] = 0.f; P[n] = 1.f; }

  for (int i = 0; i < CHUNK; ++i) {
    const size_t off = (size_t)(rowbase + i) * D_INNER + d;
    const float dt_v = dtv[off];
    const float dtxc = dt_v * xc[off];
    const float4 B0 = *(const float4*)&sB[i][0];
    const float4 B1 = *(const float4*)&sB[i][4];
    const float4 B2 = *(const float4*)&sB[i][8];
    const float4 B3 = *(const float4*)&sB[i][12];
    const float Bv[16] = {B0.x,B0.y,B0.z,B0.w, B1.x,B1.y,B1.z,B1.w,
                          B2.x,B2.y,B2.z,B2.w, B3.x,B3.y,B3.z,B3.w};
#pragma unroll
    for (int n = 0; n < 16; ++n) {
      float t = dt_v * A_d[n];
      t = fminf(fmaxf(t, -10.f), 10.f);
      const float dA = __expf(t);
      h[n] = fmaf(dA, h[n], dtxc * Bv[n]);
      P[n] *= dA;
    }
  }

  const size_t base = ((size_t)(chunk * BATCH + b) * 16) * D_INNER + d;
#pragma unroll
  for (int n = 0; n < 16; ++n) {
    Pbuf[base + (size_t)n * D_INNER] = P[n];
    Lbuf[base + (size_t)n * D_INNER] = h[n];
  }
}

// ======================================================================
// scan pass B
// ======================================================================
__global__ __launch_bounds__(256) void scanB_kernel(
    const float* __restrict__ Pbuf, const float* __restrict__ Lbuf,
    float* __restrict__ xzp)
{
  const int t = blockIdx.x * 256 + threadIdx.x;
  const int d = t & (D_INNER - 1);
  const int n = (t >> 11) & 15;
  const int b = t >> 15;
  float hs = 0.f;
#pragma unroll
  for (int c = 0; c < NCHUNK; ++c) {
    const int idx = ((c * BATCH + b) * 16 + n) * D_INNER + d;
    plh_at(xzp, idx) = hs;
    hs = fmaf(Pbuf[idx], hs, Lbuf[idx]);
  }
}

// ======================================================================
// scan pass C (chain-per-lane)
// ======================================================================
__global__ __launch_bounds__(256) void scanC_kernel(
    const float* __restrict__ dtv, const float* __restrict__ xc,
    const float* __restrict__ dbl, const float* __restrict__ A_log,
    const float* __restrict__ Dp,  float* __restrict__ xzp,
    float* __restrict__ yg)
{
  __shared__ float sBC[CHUNK][32];

  const int tid = threadIdx.x;
  const int d = blockIdx.x * 256 + tid;
  const int chunk = blockIdx.y;
  const int b = blockIdx.z;
  const int rowbase = b * SEQ + chunk * CHUNK;

  for (int idx = tid; idx < CHUNK * 32; idx += 256) {
    const int i = idx >> 5, j = idx & 31;
    sBC[i][j] = dbl[(size_t)(rowbase + i) * 96 + 64 + j];
  }

  float A_d[16];
#pragma unroll
  for (int j = 0; j < 4; ++j) {
    const float4 va = *(const float4*)&A_log[d * D_STATE + j * 4];
    A_d[j * 4 + 0] = -__expf(va.x);
    A_d[j * 4 + 1] = -__expf(va.y);
    A_d[j * 4 + 2] = -__expf(va.z);
    A_d[j * 4 + 3] = -__expf(va.w);
  }
  const float Dd = Dp[d];
  __syncthreads();

  float h[16];
  {
    const int hbase = ((chunk * BATCH + b) * 16) * D_INNER + d;
#pragma unroll
    for (int n = 0; n < 16; ++n) h[n] = plh_at(xzp, hbase + n * D_INNER);
  }

  for (int i = 0; i < CHUNK; ++i) {
    const int m = rowbase + i;
    const size_t off = (size_t)m * D_INNER + d;
    const float dt_v = dtv[off];
    const float xc_v = xc[off];
    const float dtxc = dt_v * xc_v;
    const float4 B0 = *(const float4*)&sBC[i][0];
    const float4 B1 = *(const float4*)&sBC[i][4];
    const float4 B2 = *(const float4*)&sBC[i][8];
    const float4 B3 = *(const float4*)&sBC[i][12];
    const float4 C0 = *(const float4*)&sBC[i][16];
    const float4 C1 = *(const float4*)&sBC[i][20];
    const float4 C2 = *(const float4*)&sBC[i][24];
    const float4 C3 = *(const float4*)&sBC[i][28];
    const float Bv[16] = {B0.x,B0.y,B0.z,B0.w, B1.x,B1.y,B1.z,B1.w,
                          B2.x,B2.y,B2.z,B2.w, B3.x,B3.y,B3.z,B3.w};
    const float Cv[16] = {C0.x,C0.y,C0.z,C0.w, C1.x,C1.y,C1.z,C1.w,
                          C2.x,C2.y,C2.z,C2.w, C3.x,C3.y,C3.z,C3.w};
    float y = 0.f;
#pragma unroll
    for (int n = 0; n < 16; ++n) {
      float t = dt_v * A_d[n];
      t = fminf(fmaxf(t, -10.f), 10.f);
      const float dA = __expf(t);
      h[n] = fmaf(dA, h[n], dtxc * Bv[n]);
      y = fmaf(h[n], Cv[n], y);
    }
    const float zv = xzp[(size_t)m * (2 * D_INNER) + D_INNER + d];
    const float sil = zv / (1.f + __expf(-zv));
    yg[off] = (y + xc_v * Dd) * sil;
  }
}

// ======================================================================
// RMSNorm: read yg f32, write bf16
// ======================================================================
__global__ __launch_bounds__(256) void rms_bf16_kernel(
    const float* __restrict__ yg, const float* __restrict__ rms_w,
    ushort_t* __restrict__ ygb)
{
  const int m = blockIdx.x;
  const float* row = yg + (size_t)m * D_INNER;
  const int e0 = threadIdx.x * 8;
  float4 v0 = *(const float4*)&row[e0];
  float4 v1 = *(const float4*)&row[e0 + 4];
  float ss = v0.x*v0.x + v0.y*v0.y + v0.z*v0.z + v0.w*v0.w
           + v1.x*v1.x + v1.y*v1.y + v1.z*v1.z + v1.w*v1.w;
#pragma unroll
  for (int off = 32; off > 0; off >>= 1) ss += __shfl_down(ss, off);
  __shared__ float wsum[4];
  const int lane = threadIdx.x & 63, wid = threadIdx.x >> 6;
  if (lane == 0) wsum[wid] = ss;
  __syncthreads();
  const float total = wsum[0] + wsum[1] + wsum[2] + wsum[3];
  const float scale = rsqrtf(total / (float)D_INNER + 1e-6f);
  const float4 w0 = *(const float4*)&rms_w[e0];
  const float4 w1 = *(const float4*)&rms_w[e0 + 4];
  ushort4 o0, o1;
  o0.x = f2bf(v0.x * scale * w0.x); o0.y = f2bf(v0.y * scale * w0.y);
  o0.z = f2bf(v0.z * scale * w0.z); o0.w = f2bf(v0.w * scale * w0.w);
  o1.x = f2bf(v1.x * scale * w1.x); o1.y = f2bf(v1.y * scale * w1.y);
  o1.z = f2bf(v1.z * scale * w1.z); o1.w = f2bf(v1.w * scale * w1.w);
  *(ushort4*)&ygb[(size_t)m * D_INNER + e0]     = o0;
  *(ushort4*)&ygb[(size_t)m * D_INNER + e0 + 4] = o1;
}

// ======================================================================
extern "C" void kernel_launch(void* const* d_in, const int* in_sizes, int n_in,
                              void* d_out, int out_size, void* d_ws, size_t ws_size,
                              hipStream_t stream) {
  const float* x      = (const float*)d_in[0];
  const float* W_in   = (const float*)d_in[1];
  const float* W_conv = (const float*)d_in[2];
  const float* b_conv = (const float*)d_in[3];
  const float* W_x    = (const float*)d_in[4];
  const float* W_dt   = (const float*)d_in[5];
  const float* b_dt   = (const float*)d_in[6];
  const float* A_log  = (const float*)d_in[7];
  const float* Dp     = (const float*)d_in[8];
  const float* rms_w  = (const float*)d_in[9];
  const float* W_out  = (const float*)d_in[10];
  float* out = (float*)d_out;
  float* ws  = (float*)d_ws;

  float* xz  = ws + XZ_OFF;
  float* xc  = ws + XC_OFF;
  float* dbl = ws + DBL_OFF;
  float* dt  = ws + DT_OFF;
  float* yg  = ws + YG_OFF;

  // region-reuse aliases
  ushort_t* xb      = (ushort_t*)(ws + YG_OFF);                    // bf16 x
  ushort_t* W_in_b  = (ushort_t*)(ws + YG_OFF + 1024 * 1024);      // bf16 W_in
  float*    xpart   = ws + DT_OFF;                                 // xproj partials
  float*    Pbuf    = ws + YG_OFF;                                 // scan P
  float*    Lbuf    = ws + YG_OFF + 2 * 1024 * 1024;               // scan L
  ushort_t* ygb     = (ushort_t*)(ws + DT_OFF);                    // bf16 y
  ushort_t* W_out_b = (ushort_t*)(ws + DT_OFF + 2 * 1024 * 1024);  // bf16 W_out
  float*    opart   = ws + XC_OFF;                                 // out_proj partials (2x2M, xc dead)

  // 0. convert x, W_in to bf16
  f32_to_bf16_kernel<<<(NROWS * D_MODEL / 4 + 255) / 256, 256, 0, stream>>>(x, xb, NROWS * D_MODEL / 4);
  f32_to_bf16_kernel<<<(2 * D_INNER * D_MODEL / 4 + 255) / 256, 256, 0, stream>>>(W_in, W_in_b, 2 * D_INNER * D_MODEL / 4);

  // 1. in_proj: xz = xb @ W_in_b^T (single-wave MFMA, 2048 blocks)
  {
    dim3 g((2 * D_INNER) / 64, NROWS / 64, 1);
    gemm_bf16_wave<<<g, 64, 0, stream>>>(xb, D_MODEL, W_in_b, D_MODEL, xz, 2 * D_INNER, D_MODEL);
  }
  // 2. conv + silu -> xc
  conv_silu_kernel<<<(NROWS * D_INNER) / 256, 256, 0, stream>>>(xz, W_conv, b_conv, xc);
  // 3. x_proj: dense split-K partials + reduce
  {
    dim3 g(NROWS / 64, XP_NS);
    xproj_part_kernel<<<g, 256, 0, stream>>>(xc, W_x, xpart);
    xproj_reduce_kernel<<<(NROWS * 96 / 4) / 256, 256, 0, stream>>>(xpart, dbl);
  }
  // 4. dt_proj + fused softplus -> dt
  {
    dim3 g(D_INNER / 128, NROWS / 128);
    dtproj_kernel<<<g, 256, 0, stream>>>(dbl, W_dt, b_dt, dt);
  }
  // 5. chunked selective scan (chain-per-lane)
  {
    dim3 gAC(D_INNER / 256, NCHUNK, BATCH);
    scanA_kernel<<<gAC, 256, 0, stream>>>(dt, xc, dbl, A_log, Pbuf, Lbuf);
    scanB_kernel<<<(BATCH * D_INNER * 16) / 256, 256, 0, stream>>>(Pbuf, Lbuf, xz);
    scanC_kernel<<<gAC, 256, 0, stream>>>(dt, xc, dbl, A_log, Dp, xz, yg);
  }
  // 6. RMSNorm -> bf16 ygb
  rms_bf16_kernel<<<NROWS, 256, 0, stream>>>(yg, rms_w, ygb);
  // 6b. convert W_out -> bf16
  f32_to_bf16_kernel<<<(D_MODEL * D_INNER / 4 + 255) / 256, 256, 0, stream>>>(W_out, W_out_b, D_MODEL * D_INNER / 4);
  // 7. out_proj: split-K=2 partials (xc region) + reduce -> out
  {
    dim3 g(D_MODEL / 64, NROWS / 64, 2);
    gemm_bf16_wave<<<g, 64, 0, stream>>>(ygb, D_INNER, W_out_b, D_INNER, opart, D_MODEL, D_INNER / 2);
    splitk2_reduce_kernel<<<(NROWS * D_MODEL / 4) / 256, 256, 0, stream>>>(opart, out);
  }
}